// Round 5
// baseline (235.562 us; speedup 1.0000x reference)
//
#include <hip/hip_runtime.h>
#include <stdint.h>

#define TT 512
#define BB 64
#define DD 1024
#define KK 32

__device__ __forceinline__ float rfl(float v) {
  return __int_as_float(__builtin_amdgcn_readfirstlane(__float_as_int(v)));
}

// Direct global->LDS copy, 16 B per lane.  LDS dest is wave-uniform base;
// HW writes base + lane*16 (linear lane order).  Zero VGPR staging cost.
__device__ __forceinline__ void gload_lds16(const float4* g, float4* l) {
  __builtin_amdgcn_global_load_lds(
      (const __attribute__((address_space(1))) uint32_t*)g,
      (__attribute__((address_space(3))) uint32_t*)l, 16, 0, 0);
}

// ---------------------------------------------------------------------------
// Kernel 1: emission.  F[m,k] = exp( x[m,:] @ W[:,k] + b[k] ).
// r10: r9 landed ~58us and is LDS-instruction-bound: 48 ds_read_b128 per
// 16-d chunk x 8 waves/CU x 12cyc = 31us of LDS-pipe alone (this also
// retro-explains r2's 83us = 32 waves x 512 reads x 12cyc).  Fix: lane
// tile r=8 rows x k=8 (acc[8][8]) -> 16 FMA per ds_read (vs 10.7), wave
// covers 128 rows x 32 k x d-quarter.  Chunk = 8 d: W 1KB (1 gload_lds),
// x 4KB (4 gload_lds), double-buffered, counted vmcnt(5) steady state
// (r9's proven pipeline).  Per-CU ds_reads per 128 rows: 6144 -> 4096,
// and x reads are now conflict-FREE via slot swizzle
//   slot(row=rg*8+j, half=hf) = rg*16 + ((j*2+hf) ^ (rg&7))
// staged by pre-swizzling the per-lane GLOBAL source address (LDS dest of
// gload_lds stays linear).  W reads: 4 distinct addrs on 4 distinct bank
// quads, 16-lane broadcast -> conflict-free.
// Block 256 thr = 4 waves (d-quarters), 128 rows, grid 256 = 1 block/CU
// (1 wave/SIMD -- occupancy counter ~12% BY DESIGN; pipeline is async).
// LDS 40KB = 4 waves x (x[2][256] + W[2][64]) f4.  No launch-bounds cap:
// grid-limits occupancy anyway, so let regalloc have ~110 regs, no spill.
// d-order: ascending per quarter, quarters q0..q3 -- identical to r9 ->
// absmax unchanged.
// ---------------------------------------------------------------------------
__global__ __launch_bounds__(256) void emit_kernel(
    const float* __restrict__ x, const float* __restrict__ W,
    const float* __restrict__ bias, float* __restrict__ F) {
  __shared__ float4 Ls4[2560];           // 40 KB
  const int t = threadIdx.x;
  const int l = t & 63;
  const int q = t >> 6;                  // wave id = d-quarter
  const int rg = l >> 2;                 // 16 row-groups x 8 rows
  const int kg = l & 3;                  // 4 k-groups x 8 k
  const int m0 = blockIdx.x * 128;

  float4* Lx = &Ls4[q * 640];            // x chunks: [2][256] f4
  float4* Lw = &Ls4[q * 640 + 512];      // W chunks: [2][64] f4

  // --- staging sources ---
  // W: lane l stages (d = c*8 + (l>>3), k4 = l&7): contiguous 1KB/chunk.
  const float* Wlane = W + (size_t)(q * 256 + (l >> 3)) * KK + (l & 7) * 4;
  // x inst i: slot s = i*64+l; rg_s = s>>4; v = (s&15)^(rg_s&7);
  //   row = rg_s*8 + (v>>1), halfd = v&1  (pre-swizzled source).
  const float* Xl0; const float* Xl1; const float* Xl2; const float* Xl3;
  {
    const int base_q = q * 256;
#define XSRC(i)                                                              \
    ({ int s_ = (i) * 64 + l; int rgs_ = s_ >> 4;                            \
       int v_ = (s_ & 15) ^ (rgs_ & 7);                                      \
       x + (size_t)(m0 + rgs_ * 8 + (v_ >> 1)) * DD + base_q + (v_ & 1) * 4; })
    Xl0 = XSRC(0); Xl1 = XSRC(1); Xl2 = XSRC(2); Xl3 = XSRC(3);
#undef XSRC
  }

#define STAGE(c, p) do {                                                     \
    gload_lds16((const float4*)(Wlane + (size_t)(c) * 256), Lw + (p) * 64);  \
    gload_lds16((const float4*)(Xl0 + (c) * 8), Lx + (p) * 256);             \
    gload_lds16((const float4*)(Xl1 + (c) * 8), Lx + (p) * 256 + 64);        \
    gload_lds16((const float4*)(Xl2 + (c) * 8), Lx + (p) * 256 + 128);       \
    gload_lds16((const float4*)(Xl3 + (c) * 8), Lx + (p) * 256 + 192);       \
  } while (0)

#define COMPUTE(p) do {                                                      \
    const float4* Xb = Lx + (p) * 256;                                       \
    const float4* Wb = Lw + (p) * 64;                                        \
    _Pragma("unroll")                                                        \
    for (int hf = 0; hf < 2; ++hf) {                                         \
      float4 xr[8];                                                          \
      _Pragma("unroll")                                                      \
      for (int j = 0; j < 8; ++j)                                            \
        xr[j] = Xb[rg * 16 + ((j * 2 + hf) ^ (rg & 7))];                     \
      _Pragma("unroll")                                                      \
      for (int d2 = 0; d2 < 4; ++d2) {                                       \
        const int dd = hf * 4 + d2;                                          \
        float4 wlo = Wb[dd * 8 + kg * 2];                                    \
        float4 whi = Wb[dd * 8 + kg * 2 + 1];                                \
        _Pragma("unroll")                                                    \
        for (int j = 0; j < 8; ++j) {                                        \
          const float xv = ((const float*)&xr[j])[d2];                       \
          acc[j][0] = fmaf(xv, wlo.x, acc[j][0]);                            \
          acc[j][1] = fmaf(xv, wlo.y, acc[j][1]);                            \
          acc[j][2] = fmaf(xv, wlo.z, acc[j][2]);                            \
          acc[j][3] = fmaf(xv, wlo.w, acc[j][3]);                            \
          acc[j][4] = fmaf(xv, whi.x, acc[j][4]);                            \
          acc[j][5] = fmaf(xv, whi.y, acc[j][5]);                            \
          acc[j][6] = fmaf(xv, whi.z, acc[j][6]);                            \
          acc[j][7] = fmaf(xv, whi.w, acc[j][7]);                            \
        }                                                                    \
      }                                                                      \
    }                                                                        \
  } while (0)

  float acc[8][8];
#pragma unroll
  for (int j = 0; j < 8; ++j)
#pragma unroll
    for (int k = 0; k < 8; ++k) acc[j][k] = 0.f;

  STAGE(0, 0);
  STAGE(1, 1);

#pragma unroll 1
  for (int c = 0; c < 30; ++c) {
    const int p = c & 1;
    // chunk c's 5 loads are the oldest outstanding; keep c+1's 5 in flight.
    asm volatile("s_waitcnt vmcnt(5)" ::: "memory");
    COMPUTE(p);
    asm volatile("" ::: "memory");       // keep STAGE after the ds_reads
    STAGE(c + 2, p);
  }
  asm volatile("s_waitcnt vmcnt(5)" ::: "memory");
  COMPUTE(0);                            // chunk 30
  asm volatile("s_waitcnt vmcnt(0)" ::: "memory");
  COMPUTE(1);                            // chunk 31

#undef STAGE
#undef COMPUTE

  // ---- 4-way cross-quarter reduce, two 64-row passes (32 KB region) ----
  __syncthreads();
#pragma unroll 1
  for (int half = 0; half < 2; ++half) {
    if ((rg >> 3) == half) {
      const int rl = (rg & 7) * 8;
#pragma unroll
      for (int j = 0; j < 8; ++j) {
        Ls4[q * 512 + (rl + j) * 8 + kg * 2] =
            make_float4(acc[j][0], acc[j][1], acc[j][2], acc[j][3]);
        Ls4[q * 512 + (rl + j) * 8 + kg * 2 + 1] =
            make_float4(acc[j][4], acc[j][5], acc[j][6], acc[j][7]);
      }
    }
    __syncthreads();
    {
      const int rr = t >> 2;             // 64 rows
      const int kf = (t & 3) * 2;        // f4 pair within the row
      float4 s0 = Ls4[rr * 8 + kf];
      float4 s1 = Ls4[rr * 8 + kf + 1];
#pragma unroll
      for (int qq = 1; qq < 4; ++qq) {
        float4 a0 = Ls4[qq * 512 + rr * 8 + kf];
        float4 a1 = Ls4[qq * 512 + rr * 8 + kf + 1];
        s0.x += a0.x; s0.y += a0.y; s0.z += a0.z; s0.w += a0.w;
        s1.x += a1.x; s1.y += a1.y; s1.z += a1.z; s1.w += a1.w;
      }
      float4 bb0 = *(const float4*)(bias + kf * 4);
      float4 bb1 = *(const float4*)(bias + kf * 4 + 4);
      float4 e0, e1;
      e0.x = __expf(s0.x + bb0.x); e0.y = __expf(s0.y + bb0.y);
      e0.z = __expf(s0.z + bb0.z); e0.w = __expf(s0.w + bb0.w);
      e1.x = __expf(s1.x + bb1.x); e1.y = __expf(s1.y + bb1.y);
      e1.z = __expf(s1.z + bb1.z); e1.w = __expf(s1.w + bb1.w);
      float4* F4 = (float4*)(F + (size_t)(m0 + half * 64 + rr) * KK);
      F4[kf] = e0;
      F4[kf + 1] = e1;
    }
    __syncthreads();
  }
}

// ---------------------------------------------------------------------------
// Kernel 2: segmented scaled linear-domain forward/backward recursions.
// (unchanged — correct, off the critical path)
// ---------------------------------------------------------------------------
__global__ __launch_bounds__(64) void scan_kernel(
    const float* __restrict__ F, const float* __restrict__ U,
    float* __restrict__ A, float* __restrict__ Bw) {
  __shared__ __align__(16) float cur[KK];
  const int l = threadIdx.x;
  const int kk = l & 31;
  const int h = l >> 5;
  const int seg = blockIdx.x & 15;
  const int b = (blockIdx.x >> 4) & 63;
  const int dir = blockIdx.x >> 10;

  const float* Fb = F + (size_t)b * TT * KK;
  float V[16];

  if (dir == 0) {
    float* Ab = A + (size_t)b * TT * KK;
#pragma unroll
    for (int j = 0; j < 16; ++j) V[j] = __expf(U[(h * 16 + j) * KK + kk]);
    const int lo = seg * 32, hi = seg * 32 + 31;
    const int t0 = (seg == 0) ? 0 : lo - 17;
    float a = Fb[t0 * KK + kk];
    cur[kk] = a;
    if (seg == 0 && l < 32) Ab[l] = a;
    __builtin_amdgcn_wave_barrier();

#define FSTEP(fv, tcur)                                                     \
    {                                                                       \
      const float4* c4 = (const float4*)cur;                                \
      float4 y0 = c4[h*4+0], y1 = c4[h*4+1], y2 = c4[h*4+2], y3 = c4[h*4+3];\
      float r = __builtin_amdgcn_rcpf(rfl(y0.x));                           \
      float s0 = fmaf(y0.x, V[0],  fmaf(y0.y, V[1],                         \
                 fmaf(y0.z, V[2],  y0.w * V[3])));                          \
      float s1 = fmaf(y1.x, V[4],  fmaf(y1.y, V[5],                         \
                 fmaf(y1.z, V[6],  y1.w * V[7])));                          \
      float s2 = fmaf(y2.x, V[8],  fmaf(y2.y, V[9],                         \
                 fmaf(y2.z, V[10], y2.w * V[11])));                         \
      float s3 = fmaf(y3.x, V[12], fmaf(y3.y, V[13],                        \
                 fmaf(y3.z, V[14], y3.w * V[15])));                         \
      float s = (s0 + s1) + (s2 + s3);                                      \
      s += __shfl_xor(s, 32);                                               \
      a = s * ((fv) * r);                                                   \
      cur[kk] = a;                                                          \
      __builtin_amdgcn_wave_barrier();                                      \
      if ((tcur) >= lo && l < 32) Ab[(tcur) * KK + l] = a;                  \
    }

    int t = t0 + 1;
    float f0 = Fb[t * KK + kk],       f1 = Fb[(t + 1) * KK + kk];
    float f2 = Fb[(t + 2) * KK + kk], f3 = Fb[(t + 3) * KK + kk];
    for (; t + 3 <= hi; t += 4) {
      int tn = t + 4;
      int u0 = tn     > hi ? hi : tn;
      int u1 = tn + 1 > hi ? hi : tn + 1;
      int u2 = tn + 2 > hi ? hi : tn + 2;
      int u3 = tn + 3 > hi ? hi : tn + 3;
      float n0 = Fb[u0 * KK + kk], n1 = Fb[u1 * KK + kk];
      float n2 = Fb[u2 * KK + kk], n3 = Fb[u3 * KK + kk];
      FSTEP(f0, t); FSTEP(f1, t + 1); FSTEP(f2, t + 2); FSTEP(f3, t + 3);
      f0 = n0; f1 = n1; f2 = n2; f3 = n3;
    }
    if (t <= hi) { FSTEP(f0, t); ++t; }
    if (t <= hi) { FSTEP(f1, t); ++t; }
    if (t <= hi) { FSTEP(f2, t); ++t; }
#undef FSTEP
  } else {
    const int b2 = b;
    float* Bb = Bw + (size_t)b2 * TT * KK;
#pragma unroll
    for (int j = 0; j < 16; ++j) V[j] = __expf(U[kk * KK + h * 16 + j]);
    const int lo = seg * 32;
    const int hs = seg * 32 + 31;
    const int t1 = (seg == 15) ? (TT - 1) : (lo + 48);
    float g = Fb[t1 * KK + kk];
    cur[kk] = g;
    if (seg == 15 && l < 32) Bb[(TT - 1) * KK + l] = 1.0f;
    __builtin_amdgcn_wave_barrier();

#define BSTEP(fv, tcur)                                                     \
    {                                                                       \
      const float4* c4 = (const float4*)cur;                                \
      float4 y0 = c4[h*4+0], y1 = c4[h*4+1], y2 = c4[h*4+2], y3 = c4[h*4+3];\
      float r = __builtin_amdgcn_rcpf(rfl(y0.x));                           \
      float s0 = fmaf(y0.x, V[0],  fmaf(y0.y, V[1],                         \
                 fmaf(y0.z, V[2],  y0.w * V[3])));                          \
      float s1 = fmaf(y1.x, V[4],  fmaf(y1.y, V[5],                         \
                 fmaf(y1.z, V[6],  y1.w * V[7])));                          \
      float s2 = fmaf(y2.x, V[8],  fmaf(y2.y, V[9],                         \
                 fmaf(y2.z, V[10], y2.w * V[11])));                         \
      float s3 = fmaf(y3.x, V[12], fmaf(y3.y, V[13],                        \
                 fmaf(y3.z, V[14], y3.w * V[15])));                         \
      float s = (s0 + s1) + (s2 + s3);                                      \
      s += __shfl_xor(s, 32);                                               \
      float bnew = s * r;                                                   \
      g = bnew * (fv);                                                      \
      cur[kk] = g;                                                          \
      __builtin_amdgcn_wave_barrier();                                      \
      if ((tcur) <= hs && l < 32) Bb[(tcur) * KK + l] = bnew;               \
    }

    int t = t1 - 1;
    float f0 = Fb[t * KK + kk],       f1 = Fb[(t - 1) * KK + kk];
    float f2 = Fb[(t - 2) * KK + kk], f3 = Fb[(t - 3) * KK + kk];
    for (; t - 3 >= lo; t -= 4) {
      int tn = t - 4;
      int u0 = tn     < 0 ? 0 : tn;
      int u1 = tn - 1 < 0 ? 0 : tn - 1;
      int u2 = tn - 2 < 0 ? 0 : tn - 2;
      int u3 = tn - 3 < 0 ? 0 : tn - 3;
      float n0 = Fb[u0 * KK + kk], n1 = Fb[u1 * KK + kk];
      float n2 = Fb[u2 * KK + kk], n3 = Fb[u3 * KK + kk];
      BSTEP(f0, t); BSTEP(f1, t - 1); BSTEP(f2, t - 2); BSTEP(f3, t - 3);
      f0 = n0; f1 = n1; f2 = n2; f3 = n3;
    }
    if (t >= lo) { BSTEP(f0, t); --t; }
    if (t >= lo) { BSTEP(f1, t); --t; }
    if (t >= lo) { BSTEP(f2, t); --t; }
#undef BSTEP
  }
}

// ---------------------------------------------------------------------------
// Kernel 3: marginals.  out[m,k] = A[m,k]*B[m,k] / sum_k' A[m,k']*B[m,k'].
// ---------------------------------------------------------------------------
__global__ __launch_bounds__(256) void combine_kernel(
    const float* __restrict__ Bw, float* __restrict__ out) {
  size_t i = (size_t)blockIdx.x * 256 + threadIdx.x;
  float p = out[i] * Bw[i];
  float ssum = p;
  ssum += __shfl_xor(ssum, 1);
  ssum += __shfl_xor(ssum, 2);
  ssum += __shfl_xor(ssum, 4);
  ssum += __shfl_xor(ssum, 8);
  ssum += __shfl_xor(ssum, 16);
  out[i] = p / ssum;
}

extern "C" void kernel_launch(void* const* d_in, const int* in_sizes, int n_in,
                              void* d_out, int out_size, void* d_ws, size_t ws_size,
                              hipStream_t stream) {
  const float* x = (const float*)d_in[0];   // [B,T,D]
  const float* W = (const float*)d_in[1];   // [D,K]
  const float* U = (const float*)d_in[2];   // [K,K]
  const float* b = (const float*)d_in[3];   // [K]
  float* out = (float*)d_out;               // [B,T,K] — doubles as A scratch
  float* F = (float*)d_ws;                  // exp(emissions), [B*T, K] (4 MB)
  float* Bw = F + (size_t)BB * TT * KK;     // backward messages    (4 MB)

  emit_kernel<<<256, 256, 0, stream>>>(x, W, b, F);
  scan_kernel<<<2048, 64, 0, stream>>>(F, U, out, Bw);
  combine_kernel<<<(BB * TT * KK) / 256, 256, 0, stream>>>(Bw, out);
}

// Round 6
// 224.906 us; speedup vs baseline: 1.0474x; 1.0474x over previous
//
#include <hip/hip_runtime.h>
#include <stdint.h>

#define TT 512
#define BB 64
#define DD 1024
#define KK 32

typedef __attribute__((ext_vector_type(8))) short short8v;   // 8 bf16 (4 VGPR)
typedef __attribute__((ext_vector_type(4))) float f4v;       // 4 f32 acc

__device__ __forceinline__ float rfl(float v) {
  return __int_as_float(__builtin_amdgcn_readfirstlane(__float_as_int(v)));
}

// Direct global->LDS copy, 16 B per lane.  LDS dest is wave-uniform base;
// HW writes base + lane*16 (linear lane order).  Zero VGPR staging cost.
__device__ __forceinline__ void gload_lds16(const float4* g, float4* l) {
  __builtin_amdgcn_global_load_lds(
      (const __attribute__((address_space(1))) uint32_t*)g,
      (__attribute__((address_space(3))) uint32_t*)l, 16, 0, 0);
}

// Truncation split of two f32 into packed bf16-hi dword and bf16-lo dword.
// hi = top 16 bits (exact residual f-hi is fp32-representable); lo = top 16
// bits of residual -> combined ~2^-16 relative error, fp32 MFMA accumulate.
__device__ __forceinline__ void cvt2(float f0, float f1,
                                     unsigned& h, unsigned& lo) {
  unsigned u0 = __float_as_uint(f0), u1 = __float_as_uint(f1);
  h = (u1 & 0xFFFF0000u) | (u0 >> 16);
  float r0 = f0 - __uint_as_float(u0 & 0xFFFF0000u);
  float r1 = f1 - __uint_as_float(u1 & 0xFFFF0000u);
  lo = (__float_as_uint(r1) & 0xFFFF0000u) | (__float_as_uint(r0) >> 16);
}

// ---------------------------------------------------------------------------
// Kernel 0: convert W [1024][32] f32 -> bf16 hi/lo in B-fragment order.
// Frag layout for mfma_f32_16x16x32_bf16 B operand: lane l holds
// B[k = (l>>4)*8 + j][col = l&15], j=0..7.  Stored as
// Wf[(c*4 + kt*2 + hl)*64 + l] (uint4 = 8 bf16), c = d-chunk (32 d),
// kt = k-tile (16 cols), hl = hi/lo.  4096 threads total.
// ---------------------------------------------------------------------------
__global__ __launch_bounds__(256) void wconv_kernel(
    const float* __restrict__ W, uint4* __restrict__ Wf) {
  const int t = blockIdx.x * 256 + threadIdx.x;   // 0..4095
  const int l = t & 63;
  const int kt = (t >> 6) & 1;
  const int c = t >> 7;                           // 0..31
  const int d0 = c * 32 + (l >> 4) * 8;
  const int k = kt * 16 + (l & 15);
  unsigned h[4], q[4];
#pragma unroll
  for (int j = 0; j < 4; ++j) {
    float f0 = W[(size_t)(d0 + 2 * j) * KK + k];
    float f1 = W[(size_t)(d0 + 2 * j + 1) * KK + k];
    cvt2(f0, f1, h[j], q[j]);
  }
  Wf[(size_t)(c * 4 + kt * 2 + 0) * 64 + l] = make_uint4(h[0], h[1], h[2], h[3]);
  Wf[(size_t)(c * 4 + kt * 2 + 1) * 64 + l] = make_uint4(q[0], q[1], q[2], q[3]);
}

// ---------------------------------------------------------------------------
// Kernel 1: emission.  F[m,k] = exp( x[m,:] @ W[:,k] + b[k] ).
// r11: MFMA via bf16 3-term split (xh*wh + xl*wh + xh*wl, truncation split;
// logit err ~3e-5 << scan's 2e-3).  The VALU path was structurally stuck:
// FMA issue 13.7us + LDS pipe 20-30us + latency needs waves we can't fit
// (r9=58us @8w/CU, r10=91us @4w/CU).  MFMA cost: 3 x 2.15GF @2075TF =
// 3.1us -> matmul off the budget; HBM floor 21us remains.
//   Block 256 thr = 4 waves; wave owns 16 rows x 32 k, FULL d -> no
//   cross-wave reduce, no barriers.  Grid 512 = 2 blocks/CU, 8 waves/CU.
//   Chunk = 32 d (one MFMA K): x 2KB staged wave-locally (2 gload_lds,
//   XOR-swizzled global source so A-frag ds_read_b128 is bank-uniform);
//   W frag = 4 coalesced dwordx4 from wconv's layout (L2-resident).
//   Double-buffered, steady-state vmcnt(6) (never 0 in loop), 12 vmem
//   in flight/wave -> 256CU x 36KB ~ 9MB > BW*latency 5.7MB.
//   Per chunk: 2 ds_read_b128 + ~40 cvt/pack VALU + 6 MFMA
//   (2 k-tiles x {hh, lh, hl}).  D layout (m89-verified):
//   row = (l>>4)*4 + reg, col = l&15.  LDS 16KB, ~90 VGPR, no bounds cap.
// ---------------------------------------------------------------------------
__global__ __launch_bounds__(256) void emit_kernel(
    const float* __restrict__ x, const uint4* __restrict__ Wf,
    const float* __restrict__ bias, float* __restrict__ F) {
  __shared__ float4 Ls4[1024];           // 16 KB: 4 waves x 256 f4 (2 bufs)
  const int t = threadIdx.x;
  const int l = t & 63;
  const int w = t >> 6;
  const int m0 = blockIdx.x * 64;
  const int base_r = m0 + w * 16;

  float4* Lxw = &Ls4[w * 256];           // wave-local: 2 x 128 f4 buffers

  // x staging sources.  Buffer slot s (0..127): row = s>>3,
  // d-quad v = (s&7) ^ (row&7)  (XOR pre-swizzle on the GLOBAL address;
  // gload_lds dest stays linear).
  const float *xs0, *xs1;
  {
    int s = l;       int row = s >> 3; int v = (s & 7) ^ (row & 7);
    xs0 = x + (size_t)(base_r + row) * DD + v * 4;
  }
  {
    int s = 64 + l;  int row = s >> 3; int v = (s & 7) ^ (row & 7);
    xs1 = x + (size_t)(base_r + row) * DD + v * 4;
  }

  // A-frag read slots: lane l -> row r = l&15, d-group dg = l>>4;
  // b128 #0 holds d = dg*8..+3 (v = dg*2), #1 holds d = dg*8+4..+7.
  const int r_ = l & 15, dg_ = l >> 4;
  const int slot0 = r_ * 8 + ((dg_ * 2) ^ (r_ & 7));
  const int slot1 = r_ * 8 + ((dg_ * 2 + 1) ^ (r_ & 7));

  const uint4* Wp = Wf + l;

  f4v acc0 = {0.f, 0.f, 0.f, 0.f};
  f4v acc1 = {0.f, 0.f, 0.f, 0.f};

#define STAGE(c, p) do {                                                     \
    gload_lds16((const float4*)(xs0 + (c) * 32), Lxw + (p) * 128);           \
    gload_lds16((const float4*)(xs1 + (c) * 32), Lxw + (p) * 128 + 64);      \
  } while (0)

#define LOADW(c, w0, w1, w2, w3) do {                                        \
    w0 = Wp[(size_t)((c) * 4 + 0) * 64];                                     \
    w1 = Wp[(size_t)((c) * 4 + 1) * 64];                                     \
    w2 = Wp[(size_t)((c) * 4 + 2) * 64];                                     \
    w3 = Wp[(size_t)((c) * 4 + 3) * 64];                                     \
  } while (0)

#define COMPUTE(p, wh0, wl0, wh1, wl1) do {                                  \
    float4 a0 = Lxw[(p) * 128 + slot0];                                      \
    float4 a1 = Lxw[(p) * 128 + slot1];                                      \
    unsigned h0, h1, h2, h3, q0, q1, q2, q3;                                 \
    cvt2(a0.x, a0.y, h0, q0); cvt2(a0.z, a0.w, h1, q1);                      \
    cvt2(a1.x, a1.y, h2, q2); cvt2(a1.z, a1.w, h3, q3);                      \
    uint4 ahu = make_uint4(h0, h1, h2, h3);                                  \
    uint4 alu = make_uint4(q0, q1, q2, q3);                                  \
    short8v Ah = __builtin_bit_cast(short8v, ahu);                           \
    short8v Al = __builtin_bit_cast(short8v, alu);                           \
    short8v Bh0 = __builtin_bit_cast(short8v, wh0);                          \
    short8v Bl0 = __builtin_bit_cast(short8v, wl0);                          \
    short8v Bh1 = __builtin_bit_cast(short8v, wh1);                          \
    short8v Bl1 = __builtin_bit_cast(short8v, wl1);                          \
    acc0 = __builtin_amdgcn_mfma_f32_16x16x32_bf16(Ah, Bh0, acc0, 0, 0, 0);  \
    acc1 = __builtin_amdgcn_mfma_f32_16x16x32_bf16(Ah, Bh1, acc1, 0, 0, 0);  \
    acc0 = __builtin_amdgcn_mfma_f32_16x16x32_bf16(Al, Bh0, acc0, 0, 0, 0);  \
    acc1 = __builtin_amdgcn_mfma_f32_16x16x32_bf16(Al, Bh1, acc1, 0, 0, 0);  \
    acc0 = __builtin_amdgcn_mfma_f32_16x16x32_bf16(Ah, Bl0, acc0, 0, 0, 0);  \
    acc1 = __builtin_amdgcn_mfma_f32_16x16x32_bf16(Ah, Bl1, acc1, 0, 0, 0);  \
  } while (0)

  uint4 wa0, wa1, wa2, wa3;              // W frag buffer A (even chunks)
  uint4 wb0, wb1, wb2, wb3;              // W frag buffer B (odd chunks)

  STAGE(0, 0);
  LOADW(0, wa0, wa1, wa2, wa3);
  STAGE(1, 1);
  LOADW(1, wb0, wb1, wb2, wb3);

#pragma unroll 1
  for (int c = 0; c < 30; c += 2) {
    asm volatile("s_waitcnt vmcnt(6)" ::: "memory");
    COMPUTE(0, wa0, wa1, wa2, wa3);
    asm volatile("" ::: "memory");
    STAGE(c + 2, 0);
    LOADW(c + 2, wa0, wa1, wa2, wa3);
    asm volatile("s_waitcnt vmcnt(6)" ::: "memory");
    COMPUTE(1, wb0, wb1, wb2, wb3);
    asm volatile("" ::: "memory");
    STAGE(c + 3, 1);
    LOADW(c + 3, wb0, wb1, wb2, wb3);
  }
  asm volatile("s_waitcnt vmcnt(6)" ::: "memory");
  COMPUTE(0, wa0, wa1, wa2, wa3);        // chunk 30
  asm volatile("s_waitcnt vmcnt(0)" ::: "memory");
  COMPUTE(1, wb0, wb1, wb2, wb3);        // chunk 31

#undef STAGE
#undef LOADW
#undef COMPUTE

  // ---- epilogue: bias + exp + store (D: row=(l>>4)*4+j, col=l&15) ----
  const int col = l & 15;
  const int rb = base_r + (l >> 4) * 4;
  const float b0 = bias[col];
  const float b1 = bias[col + 16];
#pragma unroll
  for (int j = 0; j < 4; ++j) {
    F[(size_t)(rb + j) * KK + col]      = __expf(acc0[j] + b0);
    F[(size_t)(rb + j) * KK + col + 16] = __expf(acc1[j] + b1);
  }
}

// ---------------------------------------------------------------------------
// Kernel 2: segmented scaled linear-domain forward/backward recursions.
// (unchanged — correct, off the critical path)
// ---------------------------------------------------------------------------
__global__ __launch_bounds__(64) void scan_kernel(
    const float* __restrict__ F, const float* __restrict__ U,
    float* __restrict__ A, float* __restrict__ Bw) {
  __shared__ __align__(16) float cur[KK];
  const int l = threadIdx.x;
  const int kk = l & 31;
  const int h = l >> 5;
  const int seg = blockIdx.x & 15;
  const int b = (blockIdx.x >> 4) & 63;
  const int dir = blockIdx.x >> 10;

  const float* Fb = F + (size_t)b * TT * KK;
  float V[16];

  if (dir == 0) {
    float* Ab = A + (size_t)b * TT * KK;
#pragma unroll
    for (int j = 0; j < 16; ++j) V[j] = __expf(U[(h * 16 + j) * KK + kk]);
    const int lo = seg * 32, hi = seg * 32 + 31;
    const int t0 = (seg == 0) ? 0 : lo - 17;
    float a = Fb[t0 * KK + kk];
    cur[kk] = a;
    if (seg == 0 && l < 32) Ab[l] = a;
    __builtin_amdgcn_wave_barrier();

#define FSTEP(fv, tcur)                                                     \
    {                                                                       \
      const float4* c4 = (const float4*)cur;                                \
      float4 y0 = c4[h*4+0], y1 = c4[h*4+1], y2 = c4[h*4+2], y3 = c4[h*4+3];\
      float r = __builtin_amdgcn_rcpf(rfl(y0.x));                           \
      float s0 = fmaf(y0.x, V[0],  fmaf(y0.y, V[1],                         \
                 fmaf(y0.z, V[2],  y0.w * V[3])));                          \
      float s1 = fmaf(y1.x, V[4],  fmaf(y1.y, V[5],                         \
                 fmaf(y1.z, V[6],  y1.w * V[7])));                          \
      float s2 = fmaf(y2.x, V[8],  fmaf(y2.y, V[9],                         \
                 fmaf(y2.z, V[10], y2.w * V[11])));                         \
      float s3 = fmaf(y3.x, V[12], fmaf(y3.y, V[13],                        \
                 fmaf(y3.z, V[14], y3.w * V[15])));                         \
      float s = (s0 + s1) + (s2 + s3);                                      \
      s += __shfl_xor(s, 32);                                               \
      a = s * ((fv) * r);                                                   \
      cur[kk] = a;                                                          \
      __builtin_amdgcn_wave_barrier();                                      \
      if ((tcur) >= lo && l < 32) Ab[(tcur) * KK + l] = a;                  \
    }

    int t = t0 + 1;
    float f0 = Fb[t * KK + kk],       f1 = Fb[(t + 1) * KK + kk];
    float f2 = Fb[(t + 2) * KK + kk], f3 = Fb[(t + 3) * KK + kk];
    for (; t + 3 <= hi; t += 4) {
      int tn = t + 4;
      int u0 = tn     > hi ? hi : tn;
      int u1 = tn + 1 > hi ? hi : tn + 1;
      int u2 = tn + 2 > hi ? hi : tn + 2;
      int u3 = tn + 3 > hi ? hi : tn + 3;
      float n0 = Fb[u0 * KK + kk], n1 = Fb[u1 * KK + kk];
      float n2 = Fb[u2 * KK + kk], n3 = Fb[u3 * KK + kk];
      FSTEP(f0, t); FSTEP(f1, t + 1); FSTEP(f2, t + 2); FSTEP(f3, t + 3);
      f0 = n0; f1 = n1; f2 = n2; f3 = n3;
    }
    if (t <= hi) { FSTEP(f0, t); ++t; }
    if (t <= hi) { FSTEP(f1, t); ++t; }
    if (t <= hi) { FSTEP(f2, t); ++t; }
#undef FSTEP
  } else {
    const int b2 = b;
    float* Bb = Bw + (size_t)b2 * TT * KK;
#pragma unroll
    for (int j = 0; j < 16; ++j) V[j] = __expf(U[kk * KK + h * 16 + j]);
    const int lo = seg * 32;
    const int hs = seg * 32 + 31;
    const int t1 = (seg == 15) ? (TT - 1) : (lo + 48);
    float g = Fb[t1 * KK + kk];
    cur[kk] = g;
    if (seg == 15 && l < 32) Bb[(TT - 1) * KK + l] = 1.0f;
    __builtin_amdgcn_wave_barrier();

#define BSTEP(fv, tcur)                                                     \
    {                                                                       \
      const float4* c4 = (const float4*)cur;                                \
      float4 y0 = c4[h*4+0], y1 = c4[h*4+1], y2 = c4[h*4+2], y3 = c4[h*4+3];\
      float r = __builtin_amdgcn_rcpf(rfl(y0.x));                           \
      float s0 = fmaf(y0.x, V[0],  fmaf(y0.y, V[1],                         \
                 fmaf(y0.z, V[2],  y0.w * V[3])));                          \
      float s1 = fmaf(y1.x, V[4],  fmaf(y1.y, V[5],                         \
                 fmaf(y1.z, V[6],  y1.w * V[7])));                          \
      float s2 = fmaf(y2.x, V[8],  fmaf(y2.y, V[9],                         \
                 fmaf(y2.z, V[10], y2.w * V[11])));                         \
      float s3 = fmaf(y3.x, V[12], fmaf(y3.y, V[13],                        \
                 fmaf(y3.z, V[14], y3.w * V[15])));                         \
      float s = (s0 + s1) + (s2 + s3);                                      \
      s += __shfl_xor(s, 32);                                               \
      float bnew = s * r;                                                   \
      g = bnew * (fv);                                                      \
      cur[kk] = g;                                                          \
      __builtin_amdgcn_wave_barrier();                                      \
      if ((tcur) <= hs && l < 32) Bb[(tcur) * KK + l] = bnew;               \
    }

    int t = t1 - 1;
    float f0 = Fb[t * KK + kk],       f1 = Fb[(t - 1) * KK + kk];
    float f2 = Fb[(t - 2) * KK + kk], f3 = Fb[(t - 3) * KK + kk];
    for (; t - 3 >= lo; t -= 4) {
      int tn = t - 4;
      int u0 = tn     < 0 ? 0 : tn;
      int u1 = tn - 1 < 0 ? 0 : tn - 1;
      int u2 = tn - 2 < 0 ? 0 : tn - 2;
      int u3 = tn - 3 < 0 ? 0 : tn - 3;
      float n0 = Fb[u0 * KK + kk], n1 = Fb[u1 * KK + kk];
      float n2 = Fb[u2 * KK + kk], n3 = Fb[u3 * KK + kk];
      BSTEP(f0, t); BSTEP(f1, t - 1); BSTEP(f2, t - 2); BSTEP(f3, t - 3);
      f0 = n0; f1 = n1; f2 = n2; f3 = n3;
    }
    if (t >= lo) { BSTEP(f0, t); --t; }
    if (t >= lo) { BSTEP(f1, t); --t; }
    if (t >= lo) { BSTEP(f2, t); --t; }
#undef BSTEP
  }
}

// ---------------------------------------------------------------------------
// Kernel 3: marginals.  out[m,k] = A[m,k]*B[m,k] / sum_k' A[m,k']*B[m,k'].
// ---------------------------------------------------------------------------
__global__ __launch_bounds__(256) void combine_kernel(
    const float* __restrict__ Bw, float* __restrict__ out) {
  size_t i = (size_t)blockIdx.x * 256 + threadIdx.x;
  float p = out[i] * Bw[i];
  float ssum = p;
  ssum += __shfl_xor(ssum, 1);
  ssum += __shfl_xor(ssum, 2);
  ssum += __shfl_xor(ssum, 4);
  ssum += __shfl_xor(ssum, 8);
  ssum += __shfl_xor(ssum, 16);
  out[i] = p / ssum;
}

extern "C" void kernel_launch(void* const* d_in, const int* in_sizes, int n_in,
                              void* d_out, int out_size, void* d_ws, size_t ws_size,
                              hipStream_t stream) {
  const float* x = (const float*)d_in[0];   // [B,T,D]
  const float* W = (const float*)d_in[1];   // [D,K]
  const float* U = (const float*)d_in[2];   // [K,K]
  const float* b = (const float*)d_in[3];   // [K]
  float* out = (float*)d_out;               // [B,T,K] — doubles as A scratch
  float* F = (float*)d_ws;                  // exp(emissions), [B*T, K] (4 MB)
  float* Bw = F + (size_t)BB * TT * KK;     // backward messages    (4 MB)
  uint4* Wf = (uint4*)(Bw + (size_t)BB * TT * KK);  // W bf16 frags (128 KB)

  wconv_kernel<<<16, 256, 0, stream>>>(W, Wf);
  emit_kernel<<<512, 256, 0, stream>>>(x, Wf, b, F);
  scan_kernel<<<2048, 64, 0, stream>>>(F, U, out, Bw);
  combine_kernel<<<(BB * TT * KK) / 256, 256, 0, stream>>>(Bw, out);
}

// Round 7
// 218.524 us; speedup vs baseline: 1.0780x; 1.0292x over previous
//
#include <hip/hip_runtime.h>
#include <stdint.h>

#define TT 512
#define BB 64
#define DD 1024
#define KK 32

typedef __attribute__((ext_vector_type(8))) short short8v;   // 8 bf16 (4 VGPR)
typedef __attribute__((ext_vector_type(4))) float f4v;       // 4 f32 acc

__device__ __forceinline__ float rfl(float v) {
  return __int_as_float(__builtin_amdgcn_readfirstlane(__float_as_int(v)));
}

// Truncation split of two f32 into packed bf16-hi dword and bf16-lo dword.
// hi = top 16 bits; lo = top 16 bits of residual -> ~2^-16 relative error,
// fp32 MFMA accumulate.  (Validated r11: absmax bit-identical to VALU path.)
__device__ __forceinline__ void cvt2(float f0, float f1,
                                     unsigned& h, unsigned& lo) {
  unsigned u0 = __float_as_uint(f0), u1 = __float_as_uint(f1);
  h = (u1 & 0xFFFF0000u) | (u0 >> 16);
  float r0 = f0 - __uint_as_float(u0 & 0xFFFF0000u);
  float r1 = f1 - __uint_as_float(u1 & 0xFFFF0000u);
  lo = (__float_as_uint(r1) & 0xFFFF0000u) | (__float_as_uint(r0) >> 16);
}

// ---------------------------------------------------------------------------
// Kernel 0: convert W [1024][32] f32 -> bf16 hi/lo in B-fragment order.
// Frag layout for mfma_f32_16x16x32_bf16 B operand: lane l holds
// B[k = (l>>4)*8 + j][col = l&15], j=0..7.  Stored as
// Wf[(c*4 + kt*2 + hl)*64 + l] (uint4 = 8 bf16), c = d-chunk (32 d),
// kt = k-tile (16 cols), hl = hi/lo.  (unchanged from r11, validated)
// ---------------------------------------------------------------------------
__global__ __launch_bounds__(256) void wconv_kernel(
    const float* __restrict__ W, uint4* __restrict__ Wf) {
  const int t = blockIdx.x * 256 + threadIdx.x;   // 0..4095
  const int l = t & 63;
  const int kt = (t >> 6) & 1;
  const int c = t >> 7;                           // 0..31
  const int d0 = c * 32 + (l >> 4) * 8;
  const int k = kt * 16 + (l & 15);
  unsigned h[4], q[4];
#pragma unroll
  for (int j = 0; j < 4; ++j) {
    float f0 = W[(size_t)(d0 + 2 * j) * KK + k];
    float f1 = W[(size_t)(d0 + 2 * j + 1) * KK + k];
    cvt2(f0, f1, h[j], q[j]);
  }
  Wf[(size_t)(c * 4 + kt * 2 + 0) * 64 + l] = make_uint4(h[0], h[1], h[2], h[3]);
  Wf[(size_t)(c * 4 + kt * 2 + 1) * 64 + l] = make_uint4(q[0], q[1], q[2], q[3]);
}

// ---------------------------------------------------------------------------
// Kernel 1: emission.  F[m,k] = exp( x[m,:] @ W[:,k] + b[k] ).
// r12: r11's MFMA emit was numerically perfect but ~60us -- no faster than
// the VALU version.  Traced cause: effective x-prefetch depth ~1 chunk
// (STAGE(c+2) waited on ~250cyc later vs ~900cyc HBM latency), ~24KB/CU in
// flight vs 9.2KB BW*latency minimum, 8 waves/CU, 16 inline-asm waitcnts
// constraining the scheduler.  Fix: A-fragment layout (lane: row=l&15,
// k=(l>>4)*8+j) is DIRECTLY loadable from global -- the LDS round trip was
// only needed by the old VALU broadcast pattern.  So: no LDS staging, no
// gload_lds, no inline asm.  Per chunk (32 d): 2 coalesced dwordx4 x-loads
// straight into the fragment, 4 dwordx4 W-frag loads (L2-resident Wf).
// x depth 4 (xa[4][2], static via full unroll), W depth 2.  Compiler emits
// its own counted vmcnt for the rotation (G7).
//   Block 256 = 4 waves = 2 row-tiles x 2 d-halves; 32 rows/block; grid
//   1024 -> 4 blocks/CU, 16 waves/CU.  In-flight x ~8KB/wave x 16 waves =
//   128KB/CU ~ 14x BW*latency -> BW-sustainable even at loaded latency.
//   Epilogue: d-half pair reduce via 8KB LDS, then bias+exp+store
//   (D layout m89: row=(l>>4)*4+reg, col=l&15 -- validated r11).
//   ~100 VGPR est; __launch_bounds__(256,4) caps at 128 (16 waves/CU).
//   d-half sum reorder vs full-ascending: ~2^-24 rel; absmax scan-bound.
// ---------------------------------------------------------------------------
__global__ __launch_bounds__(256, 4) void emit_kernel(
    const float* __restrict__ x, const uint4* __restrict__ Wf,
    const float* __restrict__ bias, float* __restrict__ F) {
  __shared__ float Ls[4 * 64 * 8];       // 8 KB: per-wave per-lane 8 partials
  const int t = threadIdx.x;
  const int l = t & 63;
  const int w = t >> 6;                  // wave id
  const int rt = w >> 1;                 // row-tile (0,1)
  const int h = w & 1;                   // d-half (0,1)
  const int m0 = blockIdx.x * 32;
  const int base_r = m0 + rt * 16;

  // A-frag source: lane l covers row base_r + (l&15), k-group l>>4.
  const float* xp = x + (size_t)(base_r + (l & 15)) * DD + h * 512 + (l >> 4) * 8;
  const uint4* Wp = Wf + l;

  f4v acc0 = {0.f, 0.f, 0.f, 0.f};
  f4v acc1 = {0.f, 0.f, 0.f, 0.f};

  float4 xa[4][2];                       // 4-deep x fragment pipeline
  uint4 wv[2][4];                        // 2-deep W fragment pipeline
#pragma unroll
  for (int i = 0; i < 4; ++i) {
    xa[i][0] = *(const float4*)(xp + i * 32);
    xa[i][1] = *(const float4*)(xp + i * 32 + 4);
  }
#pragma unroll
  for (int i = 0; i < 2; ++i)
#pragma unroll
    for (int j = 0; j < 4; ++j)
      wv[i][j] = Wp[(size_t)((h * 16 + i) * 4 + j) * 64];

#pragma unroll
  for (int c = 0; c < 16; ++c) {
    const float4 a0 = xa[c & 3][0];
    const float4 a1 = xa[c & 3][1];
    unsigned h0, h1, h2, h3, q0, q1, q2, q3;
    cvt2(a0.x, a0.y, h0, q0); cvt2(a0.z, a0.w, h1, q1);
    cvt2(a1.x, a1.y, h2, q2); cvt2(a1.z, a1.w, h3, q3);
    const uint4 ahu = make_uint4(h0, h1, h2, h3);
    const uint4 alu = make_uint4(q0, q1, q2, q3);
    const short8v Ah = __builtin_bit_cast(short8v, ahu);
    const short8v Al = __builtin_bit_cast(short8v, alu);
    const short8v Bh0 = __builtin_bit_cast(short8v, wv[c & 1][0]);
    const short8v Bl0 = __builtin_bit_cast(short8v, wv[c & 1][1]);
    const short8v Bh1 = __builtin_bit_cast(short8v, wv[c & 1][2]);
    const short8v Bl1 = __builtin_bit_cast(short8v, wv[c & 1][3]);
    // refill the just-freed pipeline slots (static indices via full unroll)
    if (c + 4 < 16) {
      xa[c & 3][0] = *(const float4*)(xp + (c + 4) * 32);
      xa[c & 3][1] = *(const float4*)(xp + (c + 4) * 32 + 4);
    }
    if (c + 2 < 16) {
#pragma unroll
      for (int j = 0; j < 4; ++j)
        wv[c & 1][j] = Wp[(size_t)((h * 16 + c + 2) * 4 + j) * 64];
    }
    acc0 = __builtin_amdgcn_mfma_f32_16x16x32_bf16(Ah, Bh0, acc0, 0, 0, 0);
    acc1 = __builtin_amdgcn_mfma_f32_16x16x32_bf16(Ah, Bh1, acc1, 0, 0, 0);
    acc0 = __builtin_amdgcn_mfma_f32_16x16x32_bf16(Al, Bh0, acc0, 0, 0, 0);
    acc1 = __builtin_amdgcn_mfma_f32_16x16x32_bf16(Al, Bh1, acc1, 0, 0, 0);
    acc0 = __builtin_amdgcn_mfma_f32_16x16x32_bf16(Ah, Bl0, acc0, 0, 0, 0);
    acc1 = __builtin_amdgcn_mfma_f32_16x16x32_bf16(Ah, Bl1, acc1, 0, 0, 0);
  }

  // ---- d-half pair reduce through LDS, then bias+exp+store ----
  {
    float* qp = Ls + (w * 64 + l) * 8;
#pragma unroll
    for (int j = 0; j < 4; ++j) { qp[j] = acc0[j]; qp[4 + j] = acc1[j]; }
  }
  __syncthreads();
  if (h == 0) {
    const float* p2 = Ls + ((w + 1) * 64 + l) * 8;
    const int col = l & 15;
    const int rb = base_r + (l >> 4) * 4;
    const float b0 = bias[col];
    const float b1 = bias[col + 16];
#pragma unroll
    for (int j = 0; j < 4; ++j) {
      F[(size_t)(rb + j) * KK + col]      = __expf(acc0[j] + p2[j]     + b0);
      F[(size_t)(rb + j) * KK + col + 16] = __expf(acc1[j] + p2[4 + j] + b1);
    }
  }
}

// ---------------------------------------------------------------------------
// Kernel 2: segmented scaled linear-domain forward/backward recursions.
// (unchanged — correct, off the critical path)
// ---------------------------------------------------------------------------
__global__ __launch_bounds__(64) void scan_kernel(
    const float* __restrict__ F, const float* __restrict__ U,
    float* __restrict__ A, float* __restrict__ Bw) {
  __shared__ __align__(16) float cur[KK];
  const int l = threadIdx.x;
  const int kk = l & 31;
  const int h = l >> 5;
  const int seg = blockIdx.x & 15;
  const int b = (blockIdx.x >> 4) & 63;
  const int dir = blockIdx.x >> 10;

  const float* Fb = F + (size_t)b * TT * KK;
  float V[16];

  if (dir == 0) {
    float* Ab = A + (size_t)b * TT * KK;
#pragma unroll
    for (int j = 0; j < 16; ++j) V[j] = __expf(U[(h * 16 + j) * KK + kk]);
    const int lo = seg * 32, hi = seg * 32 + 31;
    const int t0 = (seg == 0) ? 0 : lo - 17;
    float a = Fb[t0 * KK + kk];
    cur[kk] = a;
    if (seg == 0 && l < 32) Ab[l] = a;
    __builtin_amdgcn_wave_barrier();

#define FSTEP(fv, tcur)                                                     \
    {                                                                       \
      const float4* c4 = (const float4*)cur;                                \
      float4 y0 = c4[h*4+0], y1 = c4[h*4+1], y2 = c4[h*4+2], y3 = c4[h*4+3];\
      float r = __builtin_amdgcn_rcpf(rfl(y0.x));                           \
      float s0 = fmaf(y0.x, V[0],  fmaf(y0.y, V[1],                         \
                 fmaf(y0.z, V[2],  y0.w * V[3])));                          \
      float s1 = fmaf(y1.x, V[4],  fmaf(y1.y, V[5],                         \
                 fmaf(y1.z, V[6],  y1.w * V[7])));                          \
      float s2 = fmaf(y2.x, V[8],  fmaf(y2.y, V[9],                         \
                 fmaf(y2.z, V[10], y2.w * V[11])));                         \
      float s3 = fmaf(y3.x, V[12], fmaf(y3.y, V[13],                        \
                 fmaf(y3.z, V[14], y3.w * V[15])));                         \
      float s = (s0 + s1) + (s2 + s3);                                      \
      s += __shfl_xor(s, 32);                                               \
      a = s * ((fv) * r);                                                   \
      cur[kk] = a;                                                          \
      __builtin_amdgcn_wave_barrier();                                      \
      if ((tcur) >= lo && l < 32) Ab[(tcur) * KK + l] = a;                  \
    }

    int t = t0 + 1;
    float f0 = Fb[t * KK + kk],       f1 = Fb[(t + 1) * KK + kk];
    float f2 = Fb[(t + 2) * KK + kk], f3 = Fb[(t + 3) * KK + kk];
    for (; t + 3 <= hi; t += 4) {
      int tn = t + 4;
      int u0 = tn     > hi ? hi : tn;
      int u1 = tn + 1 > hi ? hi : tn + 1;
      int u2 = tn + 2 > hi ? hi : tn + 2;
      int u3 = tn + 3 > hi ? hi : tn + 3;
      float n0 = Fb[u0 * KK + kk], n1 = Fb[u1 * KK + kk];
      float n2 = Fb[u2 * KK + kk], n3 = Fb[u3 * KK + kk];
      FSTEP(f0, t); FSTEP(f1, t + 1); FSTEP(f2, t + 2); FSTEP(f3, t + 3);
      f0 = n0; f1 = n1; f2 = n2; f3 = n3;
    }
    if (t <= hi) { FSTEP(f0, t); ++t; }
    if (t <= hi) { FSTEP(f1, t); ++t; }
    if (t <= hi) { FSTEP(f2, t); ++t; }
#undef FSTEP
  } else {
    const int b2 = b;
    float* Bb = Bw + (size_t)b2 * TT * KK;
#pragma unroll
    for (int j = 0; j < 16; ++j) V[j] = __expf(U[kk * KK + h * 16 + j]);
    const int lo = seg * 32;
    const int hs = seg * 32 + 31;
    const int t1 = (seg == 15) ? (TT - 1) : (lo + 48);
    float g = Fb[t1 * KK + kk];
    cur[kk] = g;
    if (seg == 15 && l < 32) Bb[(TT - 1) * KK + l] = 1.0f;
    __builtin_amdgcn_wave_barrier();

#define BSTEP(fv, tcur)                                                     \
    {                                                                       \
      const float4* c4 = (const float4*)cur;                                \
      float4 y0 = c4[h*4+0], y1 = c4[h*4+1], y2 = c4[h*4+2], y3 = c4[h*4+3];\
      float r = __builtin_amdgcn_rcpf(rfl(y0.x));                           \
      float s0 = fmaf(y0.x, V[0],  fmaf(y0.y, V[1],                         \
                 fmaf(y0.z, V[2],  y0.w * V[3])));                          \
      float s1 = fmaf(y1.x, V[4],  fmaf(y1.y, V[5],                         \
                 fmaf(y1.z, V[6],  y1.w * V[7])));                          \
      float s2 = fmaf(y2.x, V[8],  fmaf(y2.y, V[9],                         \
                 fmaf(y2.z, V[10], y2.w * V[11])));                         \
      float s3 = fmaf(y3.x, V[12], fmaf(y3.y, V[13],                        \
                 fmaf(y3.z, V[14], y3.w * V[15])));                         \
      float s = (s0 + s1) + (s2 + s3);                                      \
      s += __shfl_xor(s, 32);                                               \
      float bnew = s * r;                                                   \
      g = bnew * (fv);                                                      \
      cur[kk] = g;                                                          \
      __builtin_amdgcn_wave_barrier();                                      \
      if ((tcur) <= hs && l < 32) Bb[(tcur) * KK + l] = bnew;               \
    }

    int t = t1 - 1;
    float f0 = Fb[t * KK + kk],       f1 = Fb[(t - 1) * KK + kk];
    float f2 = Fb[(t - 2) * KK + kk], f3 = Fb[(t - 3) * KK + kk];
    for (; t - 3 >= lo; t -= 4) {
      int tn = t - 4;
      int u0 = tn     < 0 ? 0 : tn;
      int u1 = tn - 1 < 0 ? 0 : tn - 1;
      int u2 = tn - 2 < 0 ? 0 : tn - 2;
      int u3 = tn - 3 < 0 ? 0 : tn - 3;
      float n0 = Fb[u0 * KK + kk], n1 = Fb[u1 * KK + kk];
      float n2 = Fb[u2 * KK + kk], n3 = Fb[u3 * KK + kk];
      BSTEP(f0, t); BSTEP(f1, t - 1); BSTEP(f2, t - 2); BSTEP(f3, t - 3);
      f0 = n0; f1 = n1; f2 = n2; f3 = n3;
    }
    if (t >= lo) { BSTEP(f0, t); --t; }
    if (t >= lo) { BSTEP(f1, t); --t; }
    if (t >= lo) { BSTEP(f2, t); --t; }
#undef BSTEP
  }
}

// ---------------------------------------------------------------------------
// Kernel 3: marginals.  out[m,k] = A[m,k]*B[m,k] / sum_k' A[m,k']*B[m,k'].
// ---------------------------------------------------------------------------
__global__ __launch_bounds__(256) void combine_kernel(
    const float* __restrict__ Bw, float* __restrict__ out) {
  size_t i = (size_t)blockIdx.x * 256 + threadIdx.x;
  float p = out[i] * Bw[i];
  float ssum = p;
  ssum += __shfl_xor(ssum, 1);
  ssum += __shfl_xor(ssum, 2);
  ssum += __shfl_xor(ssum, 4);
  ssum += __shfl_xor(ssum, 8);
  ssum += __shfl_xor(ssum, 16);
  out[i] = p / ssum;
}

extern "C" void kernel_launch(void* const* d_in, const int* in_sizes, int n_in,
                              void* d_out, int out_size, void* d_ws, size_t ws_size,
                              hipStream_t stream) {
  const float* x = (const float*)d_in[0];   // [B,T,D]
  const float* W = (const float*)d_in[1];   // [D,K]
  const float* U = (const float*)d_in[2];   // [K,K]
  const float* b = (const float*)d_in[3];   // [K]
  float* out = (float*)d_out;               // [B,T,K] — doubles as A scratch
  float* F = (float*)d_ws;                  // exp(emissions), [B*T, K] (4 MB)
  float* Bw = F + (size_t)BB * TT * KK;     // backward messages    (4 MB)
  uint4* Wf = (uint4*)(Bw + (size_t)BB * TT * KK);  // W bf16 frags (128 KB)

  wconv_kernel<<<16, 256, 0, stream>>>(W, Wf);
  emit_kernel<<<1024, 256, 0, stream>>>(x, Wf, b, F);
  scan_kernel<<<2048, 64, 0, stream>>>(F, U, out, Bw);
  combine_kernel<<<(BB * TT * KK) / 256, 256, 0, stream>>>(Bw, out);
}

// Round 9
// 214.370 us; speedup vs baseline: 1.0989x; 1.0194x over previous
//
#include <hip/hip_runtime.h>
#include <stdint.h>

#define TT 512
#define BB 64
#define DD 1024
#define KK 32

typedef __attribute__((ext_vector_type(8))) short short8v;   // 8 bf16 (4 VGPR)
typedef __attribute__((ext_vector_type(4))) float f4v;       // 4 f32 acc

__device__ __forceinline__ float rfl(float v) {
  return __int_as_float(__builtin_amdgcn_readfirstlane(__float_as_int(v)));
}

// Direct global->LDS copy, 16 B per lane.  LDS dest is wave-uniform base;
// HW writes base + lane*16 (linear lane order).  Zero VGPR staging cost.
__device__ __forceinline__ void gload_lds16(const float4* g, float4* l) {
  __builtin_amdgcn_global_load_lds(
      (const __attribute__((address_space(1))) uint32_t*)g,
      (__attribute__((address_space(3))) uint32_t*)l, 16, 0, 0);
}

// Truncation split of two f32 into packed bf16-hi dword and bf16-lo dword.
// (Validated r11/r12: absmax bit-identical to the VALU path.)
__device__ __forceinline__ void cvt2(float f0, float f1,
                                     unsigned& h, unsigned& lo) {
  unsigned u0 = __float_as_uint(f0), u1 = __float_as_uint(f1);
  h = (u1 & 0xFFFF0000u) | (u0 >> 16);
  float r0 = f0 - __uint_as_float(u0 & 0xFFFF0000u);
  float r1 = f1 - __uint_as_float(u1 & 0xFFFF0000u);
  lo = (__float_as_uint(r1) & 0xFFFF0000u) | (__float_as_uint(r0) >> 16);
}

// ---------------------------------------------------------------------------
// Kernel 0: convert W [1024][32] f32 -> bf16 hi/lo in B-fragment order.
// (unchanged from r11, validated)
// ---------------------------------------------------------------------------
__global__ __launch_bounds__(256) void wconv_kernel(
    const float* __restrict__ W, uint4* __restrict__ Wf) {
  const int t = blockIdx.x * 256 + threadIdx.x;   // 0..4095
  const int l = t & 63;
  const int kt = (t >> 6) & 1;
  const int c = t >> 7;                           // 0..31
  const int d0 = c * 32 + (l >> 4) * 8;
  const int k = kt * 16 + (l & 15);
  unsigned h[4], q[4];
#pragma unroll
  for (int j = 0; j < 4; ++j) {
    float f0 = W[(size_t)(d0 + 2 * j) * KK + k];
    float f1 = W[(size_t)(d0 + 2 * j + 1) * KK + k];
    cvt2(f0, f1, h[j], q[j]);
  }
  Wf[(size_t)(c * 4 + kt * 2 + 0) * 64 + l] = make_uint4(h[0], h[1], h[2], h[3]);
  Wf[(size_t)(c * 4 + kt * 2 + 1) * 64 + l] = make_uint4(q[0], q[1], q[2], q[3]);
}

// ---------------------------------------------------------------------------
// Kernel 1: emission.  F[m,k] = exp( x[m,:] @ W[:,k] + b[k] ).
// r14 == r13 resubmit (round-8 bench died in harness orchestration, no
// kernel verdict; audit found no OOB/hang path).  Rationale unchanged:
// r9/r11/r12 all pinned at emit ~50-55us across radically different
// schedules -> the invariant was DRAM granularity: every variant read x in
// 128B slivers (fragment rows 4KB apart), ~65K concurrent 128B streams =
// activate-bound, ~2.5 TB/s effective.  Fix: stage the WHOLE 16-row x-tile
// (64KB LDS) up front with 1KB-contiguous gload_lds instructions (one
// quarter-row each; wave w stages rows 4w..4w+3, 16 instrs).  One
// __syncthreads (vmcnt0 drain is covered by the other resident block:
// 2 blocks/CU by LDS, 8 waves/CU, 2048 blocks = 8 slots/CU).  Compute:
// wave w = d-quarter, 8 K-steps x 6 MFMA (bf16 3-term split, r11-
// validated).  A-frags from LDS with XOR-chunk swizzle (chunk^(row&7),
// pre-swizzled global source; 8 bank-quads, 2-way max = free).  W frags:
// r12's wv[2][4] register rotation from L2-resident Wf -- with NO x-loads
// in flight during compute, W's compiler vmcnt waits can't drain a
// prefetch.  Epilogue: 4-way cross-quarter reduce through LDS, bias+exp,
// store by wave 0.  Sum order identical to r11 (asc d per quarter,
// q0..q3) -> absmax unchanged.  ~80 VGPR est., LDS 64KB.
// ---------------------------------------------------------------------------
__global__ __launch_bounds__(256) void emit_kernel(
    const float* __restrict__ x, const uint4* __restrict__ Wf,
    const float* __restrict__ bias, float* __restrict__ F) {
  __shared__ float4 Lx4[16 * 256];       // 64 KB: [row][qd*64 + slot]
  const int t = threadIdx.x;
  const int l = t & 63;
  const int w = t >> 6;                  // wave id = d-quarter
  const int m0 = blockIdx.x * 16;

  // ---- stage full 16x1024 x-tile; 1KB contiguous per instruction ----
  // instr i: row = 4w + (i>>2), quarter qd = i&3.  Lane l's dest slot l
  // holds logical 16B-chunk (l ^ (row&7))  (XOR swizzle via global source).
  {
    const float* xb = x + (size_t)m0 * DD;
#pragma unroll
    for (int i = 0; i < 16; ++i) {
      const int row = 4 * w + (i >> 2);
      const int qd = i & 3;
      const float* src =
          xb + (size_t)row * DD + qd * 256 + (l ^ (row & 7)) * 4;
      gload_lds16((const float4*)src, &Lx4[row * 256 + qd * 64]);
    }
  }
  __syncthreads();                       // all x staged (vmcnt0 + barrier)

  // ---- MFMA main loop: wave w covers d in [256w, 256w+256) ----
  const int r_ = l & 15, dg_ = l >> 4;
  const uint4* Wp = Wf + l;
  f4v acc0 = {0.f, 0.f, 0.f, 0.f};
  f4v acc1 = {0.f, 0.f, 0.f, 0.f};

  uint4 wv[2][4];                        // 2-K-step W pipeline (L2-resident)
#pragma unroll
  for (int i = 0; i < 2; ++i)
#pragma unroll
    for (int j = 0; j < 4; ++j)
      wv[i][j] = Wp[(size_t)((w * 8 + i) * 4 + j) * 64];

  const int abase = r_ * 256 + w * 64;   // lane's row base + quarter base
#pragma unroll
  for (int ks = 0; ks < 8; ++ks) {
    float4 a0 = Lx4[abase + ((ks * 8 + dg_ * 2 + 0) ^ (r_ & 7))];
    float4 a1 = Lx4[abase + ((ks * 8 + dg_ * 2 + 1) ^ (r_ & 7))];
    unsigned h0, h1, h2, h3, q0, q1, q2, q3;
    cvt2(a0.x, a0.y, h0, q0); cvt2(a0.z, a0.w, h1, q1);
    cvt2(a1.x, a1.y, h2, q2); cvt2(a1.z, a1.w, h3, q3);
    const uint4 ahu = make_uint4(h0, h1, h2, h3);
    const uint4 alu = make_uint4(q0, q1, q2, q3);
    const short8v Ah = __builtin_bit_cast(short8v, ahu);
    const short8v Al = __builtin_bit_cast(short8v, alu);
    const short8v Bh0 = __builtin_bit_cast(short8v, wv[ks & 1][0]);
    const short8v Bl0 = __builtin_bit_cast(short8v, wv[ks & 1][1]);
    const short8v Bh1 = __builtin_bit_cast(short8v, wv[ks & 1][2]);
    const short8v Bl1 = __builtin_bit_cast(short8v, wv[ks & 1][3]);
    if (ks + 2 < 8) {
#pragma unroll
      for (int j = 0; j < 4; ++j)
        wv[ks & 1][j] = Wp[(size_t)((w * 8 + ks + 2) * 4 + j) * 64];
    }
    acc0 = __builtin_amdgcn_mfma_f32_16x16x32_bf16(Ah, Bh0, acc0, 0, 0, 0);
    acc1 = __builtin_amdgcn_mfma_f32_16x16x32_bf16(Ah, Bh1, acc1, 0, 0, 0);
    acc0 = __builtin_amdgcn_mfma_f32_16x16x32_bf16(Al, Bh0, acc0, 0, 0, 0);
    acc1 = __builtin_amdgcn_mfma_f32_16x16x32_bf16(Al, Bh1, acc1, 0, 0, 0);
    acc0 = __builtin_amdgcn_mfma_f32_16x16x32_bf16(Ah, Bl0, acc0, 0, 0, 0);
    acc1 = __builtin_amdgcn_mfma_f32_16x16x32_bf16(Ah, Bl1, acc1, 0, 0, 0);
  }

  // ---- 4-way cross-quarter reduce through LDS (reuses x region) ----
  __syncthreads();                       // all ds_reads of x done everywhere
  {
    float* Ls = (float*)Lx4;
    float* qp = Ls + (w * 64 + l) * 8;
#pragma unroll
    for (int j = 0; j < 4; ++j) { qp[j] = acc0[j]; qp[4 + j] = acc1[j]; }
  }
  __syncthreads();
  if (w == 0) {
    const float* Ls = (const float*)Lx4;
    float s0[4], s1[4];
#pragma unroll
    for (int j = 0; j < 4; ++j) { s0[j] = acc0[j]; s1[j] = acc1[j]; }
#pragma unroll
    for (int q = 1; q < 4; ++q) {
      const float* p2 = Ls + ((q * 64 + l) * 8);
#pragma unroll
      for (int j = 0; j < 4; ++j) { s0[j] += p2[j]; s1[j] += p2[4 + j]; }
    }
    const int col = l & 15;
    const int rb = m0 + (l >> 4) * 4;
    const float b0 = bias[col];
    const float b1 = bias[col + 16];
#pragma unroll
    for (int j = 0; j < 4; ++j) {
      F[(size_t)(rb + j) * KK + col]      = __expf(s0[j] + b0);
      F[(size_t)(rb + j) * KK + col + 16] = __expf(s1[j] + b1);
    }
  }
}

// ---------------------------------------------------------------------------
// Kernel 2: segmented scaled linear-domain forward/backward recursions.
// (unchanged — correct, off the critical path)
// ---------------------------------------------------------------------------
__global__ __launch_bounds__(64) void scan_kernel(
    const float* __restrict__ F, const float* __restrict__ U,
    float* __restrict__ A, float* __restrict__ Bw) {
  __shared__ __align__(16) float cur[KK];
  const int l = threadIdx.x;
  const int kk = l & 31;
  const int h = l >> 5;
  const int seg = blockIdx.x & 15;
  const int b = (blockIdx.x >> 4) & 63;
  const int dir = blockIdx.x >> 10;

  const float* Fb = F + (size_t)b * TT * KK;
  float V[16];

  if (dir == 0) {
    float* Ab = A + (size_t)b * TT * KK;
#pragma unroll
    for (int j = 0; j < 16; ++j) V[j] = __expf(U[(h * 16 + j) * KK + kk]);
    const int lo = seg * 32, hi = seg * 32 + 31;
    const int t0 = (seg == 0) ? 0 : lo - 17;
    float a = Fb[t0 * KK + kk];
    cur[kk] = a;
    if (seg == 0 && l < 32) Ab[l] = a;
    __builtin_amdgcn_wave_barrier();

#define FSTEP(fv, tcur)                                                     \
    {                                                                       \
      const float4* c4 = (const float4*)cur;                                \
      float4 y0 = c4[h*4+0], y1 = c4[h*4+1], y2 = c4[h*4+2], y3 = c4[h*4+3];\
      float r = __builtin_amdgcn_rcpf(rfl(y0.x));                           \
      float s0 = fmaf(y0.x, V[0],  fmaf(y0.y, V[1],                         \
                 fmaf(y0.z, V[2],  y0.w * V[3])));                          \
      float s1 = fmaf(y1.x, V[4],  fmaf(y1.y, V[5],                         \
                 fmaf(y1.z, V[6],  y1.w * V[7])));                          \
      float s2 = fmaf(y2.x, V[8],  fmaf(y2.y, V[9],                         \
                 fmaf(y2.z, V[10], y2.w * V[11])));                         \
      float s3 = fmaf(y3.x, V[12], fmaf(y3.y, V[13],                        \
                 fmaf(y3.z, V[14], y3.w * V[15])));                         \
      float s = (s0 + s1) + (s2 + s3);                                      \
      s += __shfl_xor(s, 32);                                               \
      a = s * ((fv) * r);                                                   \
      cur[kk] = a;                                                          \
      __builtin_amdgcn_wave_barrier();                                      \
      if ((tcur) >= lo && l < 32) Ab[(tcur) * KK + l] = a;                  \
    }

    int t = t0 + 1;
    float f0 = Fb[t * KK + kk],       f1 = Fb[(t + 1) * KK + kk];
    float f2 = Fb[(t + 2) * KK + kk], f3 = Fb[(t + 3) * KK + kk];
    for (; t + 3 <= hi; t += 4) {
      int tn = t + 4;
      int u0 = tn     > hi ? hi : tn;
      int u1 = tn + 1 > hi ? hi : tn + 1;
      int u2 = tn + 2 > hi ? hi : tn + 2;
      int u3 = tn + 3 > hi ? hi : tn + 3;
      float n0 = Fb[u0 * KK + kk], n1 = Fb[u1 * KK + kk];
      float n2 = Fb[u2 * KK + kk], n3 = Fb[u3 * KK + kk];
      FSTEP(f0, t); FSTEP(f1, t + 1); FSTEP(f2, t + 2); FSTEP(f3, t + 3);
      f0 = n0; f1 = n1; f2 = n2; f3 = n3;
    }
    if (t <= hi) { FSTEP(f0, t); ++t; }
    if (t <= hi) { FSTEP(f1, t); ++t; }
    if (t <= hi) { FSTEP(f2, t); ++t; }
#undef FSTEP
  } else {
    const int b2 = b;
    float* Bb = Bw + (size_t)b2 * TT * KK;
#pragma unroll
    for (int j = 0; j < 16; ++j) V[j] = __expf(U[kk * KK + h * 16 + j]);
    const int lo = seg * 32;
    const int hs = seg * 32 + 31;
    const int t1 = (seg == 15) ? (TT - 1) : (lo + 48);
    float g = Fb[t1 * KK + kk];
    cur[kk] = g;
    if (seg == 15 && l < 32) Bb[(TT - 1) * KK + l] = 1.0f;
    __builtin_amdgcn_wave_barrier();

#define BSTEP(fv, tcur)                                                     \
    {                                                                       \
      const float4* c4 = (const float4*)cur;                                \
      float4 y0 = c4[h*4+0], y1 = c4[h*4+1], y2 = c4[h*4+2], y3 = c4[h*4+3];\
      float r = __builtin_amdgcn_rcpf(rfl(y0.x));                           \
      float s0 = fmaf(y0.x, V[0],  fmaf(y0.y, V[1],                         \
                 fmaf(y0.z, V[2],  y0.w * V[3])));                          \
      float s1 = fmaf(y1.x, V[4],  fmaf(y1.y, V[5],                         \
                 fmaf(y1.z, V[6],  y1.w * V[7])));                          \
      float s2 = fmaf(y2.x, V[8],  fmaf(y2.y, V[9],                         \
                 fmaf(y2.z, V[10], y2.w * V[11])));                         \
      float s3 = fmaf(y3.x, V[12], fmaf(y3.y, V[13],                        \
                 fmaf(y3.z, V[14], y3.w * V[15])));                         \
      float s = (s0 + s1) + (s2 + s3);                                      \
      s += __shfl_xor(s, 32);                                               \
      float bnew = s * r;                                                   \
      g = bnew * (fv);                                                      \
      cur[kk] = g;                                                          \
      __builtin_amdgcn_wave_barrier();                                      \
      if ((tcur) <= hs && l < 32) Bb[(tcur) * KK + l] = bnew;               \
    }

    int t = t1 - 1;
    float f0 = Fb[t * KK + kk],       f1 = Fb[(t - 1) * KK + kk];
    float f2 = Fb[(t - 2) * KK + kk], f3 = Fb[(t - 3) * KK + kk];
    for (; t - 3 >= lo; t -= 4) {
      int tn = t - 4;
      int u0 = tn     < 0 ? 0 : tn;
      int u1 = tn - 1 < 0 ? 0 : tn - 1;
      int u2 = tn - 2 < 0 ? 0 : tn - 2;
      int u3 = tn - 3 < 0 ? 0 : tn - 3;
      float n0 = Fb[u0 * KK + kk], n1 = Fb[u1 * KK + kk];
      float n2 = Fb[u2 * KK + kk], n3 = Fb[u3 * KK + kk];
      BSTEP(f0, t); BSTEP(f1, t - 1); BSTEP(f2, t - 2); BSTEP(f3, t - 3);
      f0 = n0; f1 = n1; f2 = n2; f3 = n3;
    }
    if (t >= lo) { BSTEP(f0, t); --t; }
    if (t >= lo) { BSTEP(f1, t); --t; }
    if (t >= lo) { BSTEP(f2, t); --t; }
#undef BSTEP
  }
}

// ---------------------------------------------------------------------------
// Kernel 3: marginals.  out[m,k] = A[m,k]*B[m,k] / sum_k' A[m,k']*B[m,k'].
// ---------------------------------------------------------------------------
__global__ __launch_bounds__(256) void combine_kernel(
    const float* __restrict__ Bw, float* __restrict__ out) {
  size_t i = (size_t)blockIdx.x * 256 + threadIdx.x;
  float p = out[i] * Bw[i];
  float ssum = p;
  ssum += __shfl_xor(ssum, 1);
  ssum += __shfl_xor(ssum, 2);
  ssum += __shfl_xor(ssum, 4);
  ssum += __shfl_xor(ssum, 8);
  ssum += __shfl_xor(ssum, 16);
  out[i] = p / ssum;
}

extern "C" void kernel_launch(void* const* d_in, const int* in_sizes, int n_in,
                              void* d_out, int out_size, void* d_ws, size_t ws_size,
                              hipStream_t stream) {
  const float* x = (const float*)d_in[0];   // [B,T,D]
  const float* W = (const float*)d_in[1];   // [D,K]
  const float* U = (const float*)d_in[2];   // [K,K]
  const float* b = (const float*)d_in[3];   // [K]
  float* out = (float*)d_out;               // [B,T,K] — doubles as A scratch
  float* F = (float*)d_ws;                  // exp(emissions), [B*T, K] (4 MB)
  float* Bw = F + (size_t)BB * TT * KK;     // backward messages    (4 MB)
  uint4* Wf = (uint4*)(Bw + (size_t)BB * TT * KK);  // W bf16 frags (128 KB)

  wconv_kernel<<<16, 256, 0, stream>>>(W, Wf);
  emit_kernel<<<2048, 256, 0, stream>>>(x, Wf, b, F);
  scan_kernel<<<2048, 64, 0, stream>>>(F, U, out, Bw);
  combine_kernel<<<(BB * TT * KK) / 256, 256, 0, stream>>>(Bw, out);
}

// Round 10
// 211.675 us; speedup vs baseline: 1.1128x; 1.0127x over previous
//
#include <hip/hip_runtime.h>
#include <stdint.h>

#define TT 512
#define BB 64
#define DD 1024
#define KK 32

typedef __attribute__((ext_vector_type(8))) short short8v;   // 8 bf16 (4 VGPR)
typedef __attribute__((ext_vector_type(4))) float f4v;       // 4 f32 acc

__device__ __forceinline__ float rfl(float v) {
  return __int_as_float(__builtin_amdgcn_readfirstlane(__float_as_int(v)));
}

// Non-temporal float4 load: skips L2 allocation on the streaming-miss path.
__device__ __forceinline__ float4 ntload4(const float* p) {
  f4v v = __builtin_nontemporal_load((const f4v*)p);
  return __builtin_bit_cast(float4, v);
}

// Truncation split of two f32 into packed bf16-hi dword and bf16-lo dword.
// (Validated r11/r12/r13: absmax bit-identical to the VALU path.)
__device__ __forceinline__ void cvt2(float f0, float f1,
                                     unsigned& h, unsigned& lo) {
  unsigned u0 = __float_as_uint(f0), u1 = __float_as_uint(f1);
  h = (u1 & 0xFFFF0000u) | (u0 >> 16);
  float r0 = f0 - __uint_as_float(u0 & 0xFFFF0000u);
  float r1 = f1 - __uint_as_float(u1 & 0xFFFF0000u);
  lo = (__float_as_uint(r1) & 0xFFFF0000u) | (__float_as_uint(r0) >> 16);
}

// ---------------------------------------------------------------------------
// Kernel 0: convert W [1024][32] f32 -> bf16 hi/lo in B-fragment order.
// (unchanged from r11, validated)
// ---------------------------------------------------------------------------
__global__ __launch_bounds__(256) void wconv_kernel(
    const float* __restrict__ W, uint4* __restrict__ Wf) {
  const int t = blockIdx.x * 256 + threadIdx.x;   // 0..4095
  const int l = t & 63;
  const int kt = (t >> 6) & 1;
  const int c = t >> 7;                           // 0..31
  const int d0 = c * 32 + (l >> 4) * 8;
  const int k = kt * 16 + (l & 15);
  unsigned h[4], q[4];
#pragma unroll
  for (int j = 0; j < 4; ++j) {
    float f0 = W[(size_t)(d0 + 2 * j) * KK + k];
    float f1 = W[(size_t)(d0 + 2 * j + 1) * KK + k];
    cvt2(f0, f1, h[j], q[j]);
  }
  Wf[(size_t)(c * 4 + kt * 2 + 0) * 64 + l] = make_uint4(h[0], h[1], h[2], h[3]);
  Wf[(size_t)(c * 4 + kt * 2 + 1) * 64 + l] = make_uint4(q[0], q[1], q[2], q[3]);
}

// ---------------------------------------------------------------------------
// Kernel 1: emission.  F[m,k] = exp( x[m,:] @ W[:,k] + b[k] ).
// r15: five structures (r9/r10/r11/r12/r13) all cap the x-read at
// 2.3-2.8 TB/s; compute exonerated by arithmetic (VALU 4.8us/CU, MFMA
// 0.3us, LDS 0.5us), in-flight 128KB/CU >> 9.2KB BW*latency.  Surviving
// suspects on the READ path, both attacked here:
//   (a) L2 allocation on streaming misses (never-reused lines through the
//       4MB/XCD victim/fill pipeline) -> non-temporal loads skip L2 alloc;
//   (b) r13's XOR-permuted source addresses within each 1KB burst may
//       defeat TA coalescing -> global source now PERFECTLY linear per
//       lane; the swizzle moves to the ds_write side (register staging,
//       16 float4 in flight; 64KB LDS caps residency at 2 blocks/CU so
//       VGPR pressure is irrelevant).
// LDS content is bit-identical to r13 (logical chunk c at slot c^(row&7));
// compute, epilogue, and summation order unchanged -> absmax unchanged.
// Structure: 2048 blocks x 256 thr, 16 rows/block, wave w = d-quarter,
// 8 K-steps x 6 MFMA (bf16 3-term split), W frags via wv[2][4] rotation
// from L2-resident Wf, 4-way cross-quarter reduce, bias+exp by wave 0.
// ---------------------------------------------------------------------------
__global__ __launch_bounds__(256) void emit_kernel(
    const float* __restrict__ x, const uint4* __restrict__ Wf,
    const float* __restrict__ bias, float* __restrict__ F) {
  __shared__ float4 Lx4[16 * 256];       // 64 KB: [row][qd*64 + slot]
  const int t = threadIdx.x;
  const int l = t & 63;
  const int w = t >> 6;                  // wave id = d-quarter
  const int m0 = blockIdx.x * 16;

  // ---- stage full 16x1024 x-tile: linear NT loads, swizzled ds_write ----
  // instr i: row = 4w + (i>>2), quarter qd = i&3.  Lane l reads global
  // chunk l (linear 1KB burst) and writes LDS slot l ^ (row&7)
  // (permutation within a 1KB row-quarter: conflict-free ds_write_b128).
  {
    const float* xb = x + (size_t)m0 * DD;
    float4 v[16];
#pragma unroll
    for (int i = 0; i < 16; ++i) {
      const int row = 4 * w + (i >> 2);
      const int qd = i & 3;
      v[i] = ntload4(xb + (size_t)row * DD + qd * 256 + l * 4);
    }
#pragma unroll
    for (int i = 0; i < 16; ++i) {
      const int row = 4 * w + (i >> 2);
      const int qd = i & 3;
      Lx4[row * 256 + qd * 64 + (l ^ (row & 7))] = v[i];
    }
  }
  __syncthreads();                       // all x staged

  // ---- MFMA main loop: wave w covers d in [256w, 256w+256) ----
  const int r_ = l & 15, dg_ = l >> 4;
  const uint4* Wp = Wf + l;
  f4v acc0 = {0.f, 0.f, 0.f, 0.f};
  f4v acc1 = {0.f, 0.f, 0.f, 0.f};

  uint4 wv[2][4];                        // 2-K-step W pipeline (L2-resident)
#pragma unroll
  for (int i = 0; i < 2; ++i)
#pragma unroll
    for (int j = 0; j < 4; ++j)
      wv[i][j] = Wp[(size_t)((w * 8 + i) * 4 + j) * 64];

  const int abase = r_ * 256 + w * 64;   // lane's row base + quarter base
#pragma unroll
  for (int ks = 0; ks < 8; ++ks) {
    float4 a0 = Lx4[abase + ((ks * 8 + dg_ * 2 + 0) ^ (r_ & 7))];
    float4 a1 = Lx4[abase + ((ks * 8 + dg_ * 2 + 1) ^ (r_ & 7))];
    unsigned h0, h1, h2, h3, q0, q1, q2, q3;
    cvt2(a0.x, a0.y, h0, q0); cvt2(a0.z, a0.w, h1, q1);
    cvt2(a1.x, a1.y, h2, q2); cvt2(a1.z, a1.w, h3, q3);
    const uint4 ahu = make_uint4(h0, h1, h2, h3);
    const uint4 alu = make_uint4(q0, q1, q2, q3);
    const short8v Ah = __builtin_bit_cast(short8v, ahu);
    const short8v Al = __builtin_bit_cast(short8v, alu);
    const short8v Bh0 = __builtin_bit_cast(short8v, wv[ks & 1][0]);
    const short8v Bl0 = __builtin_bit_cast(short8v, wv[ks & 1][1]);
    const short8v Bh1 = __builtin_bit_cast(short8v, wv[ks & 1][2]);
    const short8v Bl1 = __builtin_bit_cast(short8v, wv[ks & 1][3]);
    if (ks + 2 < 8) {
#pragma unroll
      for (int j = 0; j < 4; ++j)
        wv[ks & 1][j] = Wp[(size_t)((w * 8 + ks + 2) * 4 + j) * 64];
    }
    acc0 = __builtin_amdgcn_mfma_f32_16x16x32_bf16(Ah, Bh0, acc0, 0, 0, 0);
    acc1 = __builtin_amdgcn_mfma_f32_16x16x32_bf16(Ah, Bh1, acc1, 0, 0, 0);
    acc0 = __builtin_amdgcn_mfma_f32_16x16x32_bf16(Al, Bh0, acc0, 0, 0, 0);
    acc1 = __builtin_amdgcn_mfma_f32_16x16x32_bf16(Al, Bh1, acc1, 0, 0, 0);
    acc0 = __builtin_amdgcn_mfma_f32_16x16x32_bf16(Ah, Bl0, acc0, 0, 0, 0);
    acc1 = __builtin_amdgcn_mfma_f32_16x16x32_bf16(Ah, Bl1, acc1, 0, 0, 0);
  }

  // ---- 4-way cross-quarter reduce through LDS (reuses x region) ----
  __syncthreads();                       // all ds_reads of x done everywhere
  {
    float* Ls = (float*)Lx4;
    float* qp = Ls + (w * 64 + l) * 8;
#pragma unroll
    for (int j = 0; j < 4; ++j) { qp[j] = acc0[j]; qp[4 + j] = acc1[j]; }
  }
  __syncthreads();
  if (w == 0) {
    const float* Ls = (const float*)Lx4;
    float s0[4], s1[4];
#pragma unroll
    for (int j = 0; j < 4; ++j) { s0[j] = acc0[j]; s1[j] = acc1[j]; }
#pragma unroll
    for (int q = 1; q < 4; ++q) {
      const float* p2 = Ls + ((q * 64 + l) * 8);
#pragma unroll
      for (int j = 0; j < 4; ++j) { s0[j] += p2[j]; s1[j] += p2[4 + j]; }
    }
    const int col = l & 15;
    const int rb = m0 + (l >> 4) * 4;
    const float b0 = bias[col];
    const float b1 = bias[col + 16];
#pragma unroll
    for (int j = 0; j < 4; ++j) {
      F[(size_t)(rb + j) * KK + col]      = __expf(s0[j] + b0);
      F[(size_t)(rb + j) * KK + col + 16] = __expf(s1[j] + b1);
    }
  }
}

// ---------------------------------------------------------------------------
// Kernel 2: segmented scaled linear-domain forward/backward recursions.
// (unchanged — correct, off the critical path)
// ---------------------------------------------------------------------------
__global__ __launch_bounds__(64) void scan_kernel(
    const float* __restrict__ F, const float* __restrict__ U,
    float* __restrict__ A, float* __restrict__ Bw) {
  __shared__ __align__(16) float cur[KK];
  const int l = threadIdx.x;
  const int kk = l & 31;
  const int h = l >> 5;
  const int seg = blockIdx.x & 15;
  const int b = (blockIdx.x >> 4) & 63;
  const int dir = blockIdx.x >> 10;

  const float* Fb = F + (size_t)b * TT * KK;
  float V[16];

  if (dir == 0) {
    float* Ab = A + (size_t)b * TT * KK;
#pragma unroll
    for (int j = 0; j < 16; ++j) V[j] = __expf(U[(h * 16 + j) * KK + kk]);
    const int lo = seg * 32, hi = seg * 32 + 31;
    const int t0 = (seg == 0) ? 0 : lo - 17;
    float a = Fb[t0 * KK + kk];
    cur[kk] = a;
    if (seg == 0 && l < 32) Ab[l] = a;
    __builtin_amdgcn_wave_barrier();

#define FSTEP(fv, tcur)                                                     \
    {                                                                       \
      const float4* c4 = (const float4*)cur;                                \
      float4 y0 = c4[h*4+0], y1 = c4[h*4+1], y2 = c4[h*4+2], y3 = c4[h*4+3];\
      float r = __builtin_amdgcn_rcpf(rfl(y0.x));                           \
      float s0 = fmaf(y0.x, V[0],  fmaf(y0.y, V[1],                         \
                 fmaf(y0.z, V[2],  y0.w * V[3])));                          \
      float s1 = fmaf(y1.x, V[4],  fmaf(y1.y, V[5],                         \
                 fmaf(y1.z, V[6],  y1.w * V[7])));                          \
      float s2 = fmaf(y2.x, V[8],  fmaf(y2.y, V[9],                         \
                 fmaf(y2.z, V[10], y2.w * V[11])));                         \
      float s3 = fmaf(y3.x, V[12], fmaf(y3.y, V[13],                        \
                 fmaf(y3.z, V[14], y3.w * V[15])));                         \
      float s = (s0 + s1) + (s2 + s3);                                      \
      s += __shfl_xor(s, 32);                                               \
      a = s * ((fv) * r);                                                   \
      cur[kk] = a;                                                          \
      __builtin_amdgcn_wave_barrier();                                      \
      if ((tcur) >= lo && l < 32) Ab[(tcur) * KK + l] = a;                  \
    }

    int t = t0 + 1;
    float f0 = Fb[t * KK + kk],       f1 = Fb[(t + 1) * KK + kk];
    float f2 = Fb[(t + 2) * KK + kk], f3 = Fb[(t + 3) * KK + kk];
    for (; t + 3 <= hi; t += 4) {
      int tn = t + 4;
      int u0 = tn     > hi ? hi : tn;
      int u1 = tn + 1 > hi ? hi : tn + 1;
      int u2 = tn + 2 > hi ? hi : tn + 2;
      int u3 = tn + 3 > hi ? hi : tn + 3;
      float n0 = Fb[u0 * KK + kk], n1 = Fb[u1 * KK + kk];
      float n2 = Fb[u2 * KK + kk], n3 = Fb[u3 * KK + kk];
      FSTEP(f0, t); FSTEP(f1, t + 1); FSTEP(f2, t + 2); FSTEP(f3, t + 3);
      f0 = n0; f1 = n1; f2 = n2; f3 = n3;
    }
    if (t <= hi) { FSTEP(f0, t); ++t; }
    if (t <= hi) { FSTEP(f1, t); ++t; }
    if (t <= hi) { FSTEP(f2, t); ++t; }
#undef FSTEP
  } else {
    const int b2 = b;
    float* Bb = Bw + (size_t)b2 * TT * KK;
#pragma unroll
    for (int j = 0; j < 16; ++j) V[j] = __expf(U[kk * KK + h * 16 + j]);
    const int lo = seg * 32;
    const int hs = seg * 32 + 31;
    const int t1 = (seg == 15) ? (TT - 1) : (lo + 48);
    float g = Fb[t1 * KK + kk];
    cur[kk] = g;
    if (seg == 15 && l < 32) Bb[(TT - 1) * KK + l] = 1.0f;
    __builtin_amdgcn_wave_barrier();

#define BSTEP(fv, tcur)                                                     \
    {                                                                       \
      const float4* c4 = (const float4*)cur;                                \
      float4 y0 = c4[h*4+0], y1 = c4[h*4+1], y2 = c4[h*4+2], y3 = c4[h*4+3];\
      float r = __builtin_amdgcn_rcpf(rfl(y0.x));                           \
      float s0 = fmaf(y0.x, V[0],  fmaf(y0.y, V[1],                         \
                 fmaf(y0.z, V[2],  y0.w * V[3])));                          \
      float s1 = fmaf(y1.x, V[4],  fmaf(y1.y, V[5],                         \
                 fmaf(y1.z, V[6],  y1.w * V[7])));                          \
      float s2 = fmaf(y2.x, V[8],  fmaf(y2.y, V[9],                         \
                 fmaf(y2.z, V[10], y2.w * V[11])));                         \
      float s3 = fmaf(y3.x, V[12], fmaf(y3.y, V[13],                        \
                 fmaf(y3.z, V[14], y3.w * V[15])));                         \
      float s = (s0 + s1) + (s2 + s3);                                      \
      s += __shfl_xor(s, 32);                                               \
      float bnew = s * r;                                                   \
      g = bnew * (fv);                                                      \
      cur[kk] = g;                                                          \
      __builtin_amdgcn_wave_barrier();                                      \
      if ((tcur) <= hs && l < 32) Bb[(tcur) * KK + l] = bnew;               \
    }

    int t = t1 - 1;
    float f0 = Fb[t * KK + kk],       f1 = Fb[(t - 1) * KK + kk];
    float f2 = Fb[(t - 2) * KK + kk], f3 = Fb[(t - 3) * KK + kk];
    for (; t - 3 >= lo; t -= 4) {
      int tn = t - 4;
      int u0 = tn     < 0 ? 0 : tn;
      int u1 = tn - 1 < 0 ? 0 : tn - 1;
      int u2 = tn - 2 < 0 ? 0 : tn - 2;
      int u3 = tn - 3 < 0 ? 0 : tn - 3;
      float n0 = Fb[u0 * KK + kk], n1 = Fb[u1 * KK + kk];
      float n2 = Fb[u2 * KK + kk], n3 = Fb[u3 * KK + kk];
      BSTEP(f0, t); BSTEP(f1, t - 1); BSTEP(f2, t - 2); BSTEP(f3, t - 3);
      f0 = n0; f1 = n1; f2 = n2; f3 = n3;
    }
    if (t >= lo) { BSTEP(f0, t); --t; }
    if (t >= lo) { BSTEP(f1, t); --t; }
    if (t >= lo) { BSTEP(f2, t); --t; }
#undef BSTEP
  }
}

// ---------------------------------------------------------------------------
// Kernel 3: marginals.  out[m,k] = A[m,k]*B[m,k] / sum_k' A[m,k']*B[m,k'].
// ---------------------------------------------------------------------------
__global__ __launch_bounds__(256) void combine_kernel(
    const float* __restrict__ Bw, float* __restrict__ out) {
  size_t i = (size_t)blockIdx.x * 256 + threadIdx.x;
  float p = out[i] * Bw[i];
  float ssum = p;
  ssum += __shfl_xor(ssum, 1);
  ssum += __shfl_xor(ssum, 2);
  ssum += __shfl_xor(ssum, 4);
  ssum += __shfl_xor(ssum, 8);
  ssum += __shfl_xor(ssum, 16);
  out[i] = p / ssum;
}

extern "C" void kernel_launch(void* const* d_in, const int* in_sizes, int n_in,
                              void* d_out, int out_size, void* d_ws, size_t ws_size,
                              hipStream_t stream) {
  const float* x = (const float*)d_in[0];   // [B,T,D]
  const float* W = (const float*)d_in[1];   // [D,K]
  const float* U = (const float*)d_in[2];   // [K,K]
  const float* b = (const float*)d_in[3];   // [K]
  float* out = (float*)d_out;               // [B,T,K] — doubles as A scratch
  float* F = (float*)d_ws;                  // exp(emissions), [B*T, K] (4 MB)
  float* Bw = F + (size_t)BB * TT * KK;     // backward messages    (4 MB)
  uint4* Wf = (uint4*)(Bw + (size_t)BB * TT * KK);  // W bf16 frags (128 KB)

  wconv_kernel<<<16, 256, 0, stream>>>(W, Wf);
  emit_kernel<<<2048, 256, 0, stream>>>(x, Wf, b, F);
  scan_kernel<<<2048, 64, 0, stream>>>(F, U, out, Bw);
  combine_kernel<<<(BB * TT * KK) / 256, 256, 0, stream>>>(Bw, out);
}

// Round 11
// 209.879 us; speedup vs baseline: 1.1224x; 1.0086x over previous
//
#include <hip/hip_runtime.h>
#include <stdint.h>

#define TT 512
#define BB 64
#define DD 1024
#define KK 32

typedef __attribute__((ext_vector_type(8))) short short8v;   // 8 bf16 (4 VGPR)
typedef __attribute__((ext_vector_type(4))) float f4v;       // 4 f32 acc

__device__ __forceinline__ float rfl(float v) {
  return __int_as_float(__builtin_amdgcn_readfirstlane(__float_as_int(v)));
}

// Non-temporal float4 load: skips L2 allocation on the streaming-miss path.
__device__ __forceinline__ float4 ntload4(const float* p) {
  f4v v = __builtin_nontemporal_load((const f4v*)p);
  return __builtin_bit_cast(float4, v);
}

// Truncation split of two f32 into packed bf16-hi dword and bf16-lo dword.
// (Validated r11..r15: absmax bit-identical to the VALU path.)
__device__ __forceinline__ void cvt2(float f0, float f1,
                                     unsigned& h, unsigned& lo) {
  unsigned u0 = __float_as_uint(f0), u1 = __float_as_uint(f1);
  h = (u1 & 0xFFFF0000u) | (u0 >> 16);
  float r0 = f0 - __uint_as_float(u0 & 0xFFFF0000u);
  float r1 = f1 - __uint_as_float(u1 & 0xFFFF0000u);
  lo = (__float_as_uint(r1) & 0xFFFF0000u) | (__float_as_uint(r0) >> 16);
}

// ---------------------------------------------------------------------------
// Kernel 0: convert W [1024][32] f32 -> bf16 hi/lo in B-fragment order.
// (unchanged from r11, validated)
// ---------------------------------------------------------------------------
__global__ __launch_bounds__(256) void wconv_kernel(
    const float* __restrict__ W, uint4* __restrict__ Wf) {
  const int t = blockIdx.x * 256 + threadIdx.x;   // 0..4095
  const int l = t & 63;
  const int kt = (t >> 6) & 1;
  const int c = t >> 7;                           // 0..31
  const int d0 = c * 32 + (l >> 4) * 8;
  const int k = kt * 16 + (l & 15);
  unsigned h[4], q[4];
#pragma unroll
  for (int j = 0; j < 4; ++j) {
    float f0 = W[(size_t)(d0 + 2 * j) * KK + k];
    float f1 = W[(size_t)(d0 + 2 * j + 1) * KK + k];
    cvt2(f0, f1, h[j], q[j]);
  }
  Wf[(size_t)(c * 4 + kt * 2 + 0) * 64 + l] = make_uint4(h[0], h[1], h[2], h[3]);
  Wf[(size_t)(c * 4 + kt * 2 + 1) * 64 + l] = make_uint4(q[0], q[1], q[2], q[3]);
}

// ---------------------------------------------------------------------------
// Kernel 1: emission.  F[m,k] = exp( x[m,:] @ W[:,k] + b[k] ).
// r16: everything on the x path has been varied (grain 64B->1KB, depth 1->4,
// LDS/reg/direct staging, NT) at ~55us; the un-varied axis is wave count
// over the stage/drain phases -- every LDS-tile variant ran 2 blocks x
// 4 waves = 8 waves/CU, and the stage->vmcnt0->barrier->compute phase
// structure idles the read pipe (~40% issue duty vs the fill's 32-wave
// continuous 7 TB/s).  This round: 512 thr = 8 waves/block (wave =
// d-EIGHTH, 4 K-steps), same 16-row/64KB tile, grid 2048 -> 16 waves/CU;
// stage = 8 x 1KB NT loads per wave (2 rows x 4 quarters), swizzled
// ds_write (slot = l ^ (row&7), LDS content identical to r13/r15).
// Compute per wave halves -> finer phases, more issuers to interleave.
// __launch_bounds__(512,4): VGPR cap 128, est ~105, 2 blocks/CU.
// Epilogue: 8-way cross-eighth reduce (d-ascending order preserved),
// bias+exp+store by wave 0.  absmax expected unchanged (watched).
// ---------------------------------------------------------------------------
__global__ __launch_bounds__(512, 4) void emit_kernel(
    const float* __restrict__ x, const uint4* __restrict__ Wf,
    const float* __restrict__ bias, float* __restrict__ F) {
  __shared__ float4 Lx4[16 * 256];       // 64 KB: [row][qd*64 + slot]
  const int t = threadIdx.x;
  const int l = t & 63;
  const int w = t >> 6;                  // wave id 0..7 = d-eighth
  const int m0 = blockIdx.x * 16;

  // ---- stage 16x1024 x-tile: wave w stages rows 2w,2w+1 (8 x 1KB NT) ----
  {
    const float* xb = x + (size_t)m0 * DD;
    float4 v[8];
#pragma unroll
    for (int i = 0; i < 8; ++i) {
      const int row = 2 * w + (i >> 2);
      const int qd = i & 3;
      v[i] = ntload4(xb + (size_t)row * DD + qd * 256 + l * 4);
    }
#pragma unroll
    for (int i = 0; i < 8; ++i) {
      const int row = 2 * w + (i >> 2);
      const int qd = i & 3;
      Lx4[row * 256 + qd * 64 + (l ^ (row & 7))] = v[i];
    }
  }
  __syncthreads();                       // all x staged

  // ---- MFMA: wave w covers d in [128w, 128w+128) = 4 K-steps ----
  const int r_ = l & 15, dg_ = l >> 4;
  const uint4* Wp = Wf + l;
  f4v acc0 = {0.f, 0.f, 0.f, 0.f};
  f4v acc1 = {0.f, 0.f, 0.f, 0.f};

  uint4 wv[2][4];                        // 2-K-step W pipeline (L2-resident)
#pragma unroll
  for (int i = 0; i < 2; ++i)
#pragma unroll
    for (int j = 0; j < 4; ++j)
      wv[i][j] = Wp[(size_t)((w * 4 + i) * 4 + j) * 64];

  // lane's row base + quarter base + half-quarter base for this eighth
  const int abase = r_ * 256 + (w >> 1) * 64 + (w & 1) * 32;
#pragma unroll
  for (int ks = 0; ks < 4; ++ks) {
    float4 a0 = Lx4[abase + ((ks * 8 + dg_ * 2 + 0) ^ (r_ & 7))];
    float4 a1 = Lx4[abase + ((ks * 8 + dg_ * 2 + 1) ^ (r_ & 7))];
    unsigned h0, h1, h2, h3, q0, q1, q2, q3;
    cvt2(a0.x, a0.y, h0, q0); cvt2(a0.z, a0.w, h1, q1);
    cvt2(a1.x, a1.y, h2, q2); cvt2(a1.z, a1.w, h3, q3);
    const uint4 ahu = make_uint4(h0, h1, h2, h3);
    const uint4 alu = make_uint4(q0, q1, q2, q3);
    const short8v Ah = __builtin_bit_cast(short8v, ahu);
    const short8v Al = __builtin_bit_cast(short8v, alu);
    const short8v Bh0 = __builtin_bit_cast(short8v, wv[ks & 1][0]);
    const short8v Bl0 = __builtin_bit_cast(short8v, wv[ks & 1][1]);
    const short8v Bh1 = __builtin_bit_cast(short8v, wv[ks & 1][2]);
    const short8v Bl1 = __builtin_bit_cast(short8v, wv[ks & 1][3]);
    if (ks + 2 < 4) {
#pragma unroll
      for (int j = 0; j < 4; ++j)
        wv[ks & 1][j] = Wp[(size_t)((w * 4 + ks + 2) * 4 + j) * 64];
    }
    acc0 = __builtin_amdgcn_mfma_f32_16x16x32_bf16(Ah, Bh0, acc0, 0, 0, 0);
    acc1 = __builtin_amdgcn_mfma_f32_16x16x32_bf16(Ah, Bh1, acc1, 0, 0, 0);
    acc0 = __builtin_amdgcn_mfma_f32_16x16x32_bf16(Al, Bh0, acc0, 0, 0, 0);
    acc1 = __builtin_amdgcn_mfma_f32_16x16x32_bf16(Al, Bh1, acc1, 0, 0, 0);
    acc0 = __builtin_amdgcn_mfma_f32_16x16x32_bf16(Ah, Bl0, acc0, 0, 0, 0);
    acc1 = __builtin_amdgcn_mfma_f32_16x16x32_bf16(Ah, Bl1, acc1, 0, 0, 0);
  }

  // ---- 8-way cross-eighth reduce through LDS (reuses x region) ----
  __syncthreads();                       // all ds_reads of x done everywhere
  {
    float* Ls = (float*)Lx4;
    float* qp = Ls + (w * 64 + l) * 8;
#pragma unroll
    for (int j = 0; j < 4; ++j) { qp[j] = acc0[j]; qp[4 + j] = acc1[j]; }
  }
  __syncthreads();
  if (t < 64) {                          // wave 0: final reduce + store
    const float* Ls = (const float*)Lx4;
    float s0[4] = {0.f, 0.f, 0.f, 0.f};
    float s1[4] = {0.f, 0.f, 0.f, 0.f};
#pragma unroll
    for (int q = 0; q < 8; ++q) {        // ascending q = ascending d
      const float* p2 = Ls + ((q * 64 + l) * 8);
#pragma unroll
      for (int j = 0; j < 4; ++j) { s0[j] += p2[j]; s1[j] += p2[4 + j]; }
    }
    const int col = l & 15;
    const int rb = m0 + (l >> 4) * 4;
    const float b0 = bias[col];
    const float b1 = bias[col + 16];
#pragma unroll
    for (int j = 0; j < 4; ++j) {
      F[(size_t)(rb + j) * KK + col]      = __expf(s0[j] + b0);
      F[(size_t)(rb + j) * KK + col + 16] = __expf(s1[j] + b1);
    }
  }
}

// ---------------------------------------------------------------------------
// Kernel 2: segmented scaled linear-domain forward/backward recursions.
// (unchanged — correct, off the critical path)
// ---------------------------------------------------------------------------
__global__ __launch_bounds__(64) void scan_kernel(
    const float* __restrict__ F, const float* __restrict__ U,
    float* __restrict__ A, float* __restrict__ Bw) {
  __shared__ __align__(16) float cur[KK];
  const int l = threadIdx.x;
  const int kk = l & 31;
  const int h = l >> 5;
  const int seg = blockIdx.x & 15;
  const int b = (blockIdx.x >> 4) & 63;
  const int dir = blockIdx.x >> 10;

  const float* Fb = F + (size_t)b * TT * KK;
  float V[16];

  if (dir == 0) {
    float* Ab = A + (size_t)b * TT * KK;
#pragma unroll
    for (int j = 0; j < 16; ++j) V[j] = __expf(U[(h * 16 + j) * KK + kk]);
    const int lo = seg * 32, hi = seg * 32 + 31;
    const int t0 = (seg == 0) ? 0 : lo - 17;
    float a = Fb[t0 * KK + kk];
    cur[kk] = a;
    if (seg == 0 && l < 32) Ab[l] = a;
    __builtin_amdgcn_wave_barrier();

#define FSTEP(fv, tcur)                                                     \
    {                                                                       \
      const float4* c4 = (const float4*)cur;                                \
      float4 y0 = c4[h*4+0], y1 = c4[h*4+1], y2 = c4[h*4+2], y3 = c4[h*4+3];\
      float r = __builtin_amdgcn_rcpf(rfl(y0.x));                           \
      float s0 = fmaf(y0.x, V[0],  fmaf(y0.y, V[1],                         \
                 fmaf(y0.z, V[2],  y0.w * V[3])));                          \
      float s1 = fmaf(y1.x, V[4],  fmaf(y1.y, V[5],                         \
                 fmaf(y1.z, V[6],  y1.w * V[7])));                          \
      float s2 = fmaf(y2.x, V[8],  fmaf(y2.y, V[9],                         \
                 fmaf(y2.z, V[10], y2.w * V[11])));                         \
      float s3 = fmaf(y3.x, V[12], fmaf(y3.y, V[13],                        \
                 fmaf(y3.z, V[14], y3.w * V[15])));                         \
      float s = (s0 + s1) + (s2 + s3);                                      \
      s += __shfl_xor(s, 32);                                               \
      a = s * ((fv) * r);                                                   \
      cur[kk] = a;                                                          \
      __builtin_amdgcn_wave_barrier();                                      \
      if ((tcur) >= lo && l < 32) Ab[(tcur) * KK + l] = a;                  \
    }

    int t = t0 + 1;
    float f0 = Fb[t * KK + kk],       f1 = Fb[(t + 1) * KK + kk];
    float f2 = Fb[(t + 2) * KK + kk], f3 = Fb[(t + 3) * KK + kk];
    for (; t + 3 <= hi; t += 4) {
      int tn = t + 4;
      int u0 = tn     > hi ? hi : tn;
      int u1 = tn + 1 > hi ? hi : tn + 1;
      int u2 = tn + 2 > hi ? hi : tn + 2;
      int u3 = tn + 3 > hi ? hi : tn + 3;
      float n0 = Fb[u0 * KK + kk], n1 = Fb[u1 * KK + kk];
      float n2 = Fb[u2 * KK + kk], n3 = Fb[u3 * KK + kk];
      FSTEP(f0, t); FSTEP(f1, t + 1); FSTEP(f2, t + 2); FSTEP(f3, t + 3);
      f0 = n0; f1 = n1; f2 = n2; f3 = n3;
    }
    if (t <= hi) { FSTEP(f0, t); ++t; }
    if (t <= hi) { FSTEP(f1, t); ++t; }
    if (t <= hi) { FSTEP(f2, t); ++t; }
#undef FSTEP
  } else {
    const int b2 = b;
    float* Bb = Bw + (size_t)b2 * TT * KK;
#pragma unroll
    for (int j = 0; j < 16; ++j) V[j] = __expf(U[kk * KK + h * 16 + j]);
    const int lo = seg * 32;
    const int hs = seg * 32 + 31;
    const int t1 = (seg == 15) ? (TT - 1) : (lo + 48);
    float g = Fb[t1 * KK + kk];
    cur[kk] = g;
    if (seg == 15 && l < 32) Bb[(TT - 1) * KK + l] = 1.0f;
    __builtin_amdgcn_wave_barrier();

#define BSTEP(fv, tcur)                                                     \
    {                                                                       \
      const float4* c4 = (const float4*)cur;                                \
      float4 y0 = c4[h*4+0], y1 = c4[h*4+1], y2 = c4[h*4+2], y3 = c4[h*4+3];\
      float r = __builtin_amdgcn_rcpf(rfl(y0.x));                           \
      float s0 = fmaf(y0.x, V[0],  fmaf(y0.y, V[1],                         \
                 fmaf(y0.z, V[2],  y0.w * V[3])));                          \
      float s1 = fmaf(y1.x, V[4],  fmaf(y1.y, V[5],                         \
                 fmaf(y1.z, V[6],  y1.w * V[7])));                          \
      float s2 = fmaf(y2.x, V[8],  fmaf(y2.y, V[9],                         \
                 fmaf(y2.z, V[10], y2.w * V[11])));                         \
      float s3 = fmaf(y3.x, V[12], fmaf(y3.y, V[13],                        \
                 fmaf(y3.z, V[14], y3.w * V[15])));                         \
      float s = (s0 + s1) + (s2 + s3);                                      \
      s += __shfl_xor(s, 32);                                               \
      float bnew = s * r;                                                   \
      g = bnew * (fv);                                                      \
      cur[kk] = g;                                                          \
      __builtin_amdgcn_wave_barrier();                                      \
      if ((tcur) <= hs && l < 32) Bb[(tcur) * KK + l] = bnew;               \
    }

    int t = t1 - 1;
    float f0 = Fb[t * KK + kk],       f1 = Fb[(t - 1) * KK + kk];
    float f2 = Fb[(t - 2) * KK + kk], f3 = Fb[(t - 3) * KK + kk];
    for (; t - 3 >= lo; t -= 4) {
      int tn = t - 4;
      int u0 = tn     < 0 ? 0 : tn;
      int u1 = tn - 1 < 0 ? 0 : tn - 1;
      int u2 = tn - 2 < 0 ? 0 : tn - 2;
      int u3 = tn - 3 < 0 ? 0 : tn - 3;
      float n0 = Fb[u0 * KK + kk], n1 = Fb[u1 * KK + kk];
      float n2 = Fb[u2 * KK + kk], n3 = Fb[u3 * KK + kk];
      BSTEP(f0, t); BSTEP(f1, t - 1); BSTEP(f2, t - 2); BSTEP(f3, t - 3);
      f0 = n0; f1 = n1; f2 = n2; f3 = n3;
    }
    if (t >= lo) { BSTEP(f0, t); --t; }
    if (t >= lo) { BSTEP(f1, t); --t; }
    if (t >= lo) { BSTEP(f2, t); --t; }
#undef BSTEP
  }
}

// ---------------------------------------------------------------------------
// Kernel 3: marginals.  out[m,k] = A[m,k]*B[m,k] / sum_k' A[m,k']*B[m,k'].
// ---------------------------------------------------------------------------
__global__ __launch_bounds__(256) void combine_kernel(
    const float* __restrict__ Bw, float* __restrict__ out) {
  size_t i = (size_t)blockIdx.x * 256 + threadIdx.x;
  float p = out[i] * Bw[i];
  float ssum = p;
  ssum += __shfl_xor(ssum, 1);
  ssum += __shfl_xor(ssum, 2);
  ssum += __shfl_xor(ssum, 4);
  ssum += __shfl_xor(ssum, 8);
  ssum += __shfl_xor(ssum, 16);
  out[i] = p / ssum;
}

extern "C" void kernel_launch(void* const* d_in, const int* in_sizes, int n_in,
                              void* d_out, int out_size, void* d_ws, size_t ws_size,
                              hipStream_t stream) {
  const float* x = (const float*)d_in[0];   // [B,T,D]
  const float* W = (const float*)d_in[1];   // [D,K]
  const float* U = (const float*)d_in[2];   // [K,K]
  const float* b = (const float*)d_in[3];   // [K]
  float* out = (float*)d_out;               // [B,T,K] — doubles as A scratch
  float* F = (float*)d_ws;                  // exp(emissions), [B*T, K] (4 MB)
  float* Bw = F + (size_t)BB * TT * KK;     // backward messages    (4 MB)
  uint4* Wf = (uint4*)(Bw + (size_t)BB * TT * KK);  // W bf16 frags (128 KB)

  wconv_kernel<<<16, 256, 0, stream>>>(W, Wf);
  emit_kernel<<<2048, 512, 0, stream>>>(x, Wf, b, F);
  scan_kernel<<<2048, 64, 0, stream>>>(F, U, out, Bw);
  combine_kernel<<<(BB * TT * KK) / 256, 256, 0, stream>>>(Bw, out);
}